// Round 11
// baseline (155.074 us; speedup 1.0000x reference)
//
#include <hip/hip_runtime.h>
#include <hip/hip_fp16.h>

#define N_NODES 20000
#define N_EDGES 320000
#define MSG_ROW 576
#define MSG_OFF 11520000   // N_NODES * 576 : sc region of d_out (fallback msg buffer)
#define SCAN_BS 256
#define NBLK_SCAN ((N_NODES + SCAN_BS - 1) / SCAN_BS)   // 79
#define NPAD 20032         // 313 * 64
#define MT_S (NPAD * 64)   // halfs per m-slice of mT

typedef _Float16 f16;
typedef _Float16 f16x4 __attribute__((ext_vector_type(4)));
typedef _Float16 f16x8 __attribute__((ext_vector_type(8)));
typedef float f32x4 __attribute__((ext_vector_type(4)));

// weight image (f16 elems): [Wt4 12288 | W1t 2048 | Wt2 4096 | Wt3 4096 | WlT 12288 | WscT 16384]
// image byte offsets: Wt4 [0,24576) | W1t [24576,28672) | Wt2 [28672,36864) | Wt3 [36864,45056)
#define IMG_WT4_B 0
#define OFF_WLT  22528   // f16 index
#define OFF_WSCT 34816
#define WIMG_HALF 51200
#define WIMG_BYTES 102400
#define WIMG_BLOCKS 200  // 200*256 = 51200

// edge kernel LDS (bytes) — round-11: Wt4 NOT staged (A-frags read from L2-resident
// image, +24 transient VGPR), wxT copy-out split into two 24KB phases aliasing the
// dead W1t/Wt2/Wt3/H0 region. 70656 -> 46080 B => 3 blocks/CU (24 waves, 75% cap).
#define EK_W1T 0         // 4096
#define EK_WT2 4096      // 8192
#define EK_WT3 12288     // 8192
#define EK_H0  20480     // 8192
#define EK_HT  28672     // 16384
#define EK_LDS 45056
#define EK_WXT 0         // 64 edges x 384 B = 24576, aliases W1t..H0 (dead after L3/L1)

__device__ __forceinline__ float silu_f(float x) {
    return x * (1.0f / (1.0f + __expf(-x)));
}

// ============================ pre-kernel: weight image + histogram ============================

__global__ __launch_bounds__(256)
void pre_kernel(const float* __restrict__ W1, const float* __restrict__ W2,
                const float* __restrict__ W3, const float* __restrict__ W4,
                const float* __restrict__ Wl, const float* __restrict__ Wsc,
                f16* __restrict__ img,
                const int* __restrict__ eidx, int* __restrict__ counts) {
    const int b = blockIdx.x;
    if (b >= WIMG_BLOCKS) {
        const int e = (b - WIMG_BLOCKS) * 256 + threadIdx.x;
        if (e < N_EDGES) atomicAdd(&counts[eidx[N_EDGES + e]], 1);
        return;
    }
    const int p = b * 256 + threadIdx.x;
    float v;
    if (p < 12288) {                         // Wt4 [192][64] swizzled
        const int m = p >> 6, rem = p & 63, g = rem >> 3, j = rem & 7;
        const int k = ((g ^ (m & 7)) << 3) | j;
        v = W4[k * 192 + m];
    } else if (p < 14336) {                  // W1t [64][32], k>=8 -> 0
        const int q = p - 12288;
        const int m = q >> 5, rem = q & 31, g = rem >> 3, j = rem & 7;
        const int k = ((g ^ (m & 3)) << 3) | j;
        v = (k < 8) ? W1[k * 64 + m] : 0.f;
    } else if (p < 18432) {                  // Wt2 [64][64]
        const int q = p - 14336;
        const int m = q >> 6, rem = q & 63, g = rem >> 3, j = rem & 7;
        const int k = ((g ^ (m & 7)) << 3) | j;
        v = W2[k * 64 + m];
    } else if (p < 22528) {                  // Wt3 [64][64]
        const int q = p - 18432;
        const int m = q >> 6, rem = q & 63, g = rem >> 3, j = rem & 7;
        const int k = ((g ^ (m & 7)) << 3) | j;
        v = W3[k * 64 + m];
    } else if (p < OFF_WSCT) {               // WlT [l][v][u] linear (register frags)
        const int q = p - OFF_WLT;
        const int l = q >> 12, r = q & 4095, vv = r >> 6, u = r & 63;
        v = Wl[(l * 64 + u) * 64 + vv];
    } else {                                 // WscT [w][a*64+u] linear
        const int q = p - OFF_WSCT;
        const int ww = q >> 8, kk = q & 255, a = kk >> 6, u = kk & 63;
        v = Wsc[(a * 64 + u) * 64 + ww];
    }
    img[p] = (f16)v;
}

// ============================ CSR build (2 kernels) ============================

__global__ __launch_bounds__(SCAN_BS)
void scan1_kernel(const int* __restrict__ counts, int* __restrict__ offs,
                  int* __restrict__ bsum) {
    __shared__ int sm[SCAN_BS];
    const int tid = threadIdx.x;
    const int i = blockIdx.x * SCAN_BS + tid;
    const int v = (i < N_NODES) ? counts[i] : 0;
    sm[tid] = v;
    __syncthreads();
#pragma unroll
    for (int off = 1; off < SCAN_BS; off <<= 1) {
        const int t = (tid >= off) ? sm[tid - off] : 0;
        __syncthreads();
        sm[tid] += t;
        __syncthreads();
    }
    if (i < N_NODES) offs[i] = sm[tid] - v;          // block-local exclusive
    if (tid == SCAN_BS - 1) bsum[blockIdx.x] = sm[tid];
}

__global__ __launch_bounds__(SCAN_BS)
void scan3_kernel(int* __restrict__ offs, const int* __restrict__ bsum,
                  int* __restrict__ cursor) {
    __shared__ int bs[NBLK_SCAN];
    const int tid = threadIdx.x;
    if (tid < NBLK_SCAN) bs[tid] = bsum[tid];
    __syncthreads();
    int bbase = 0;
    for (int j = 0; j < blockIdx.x; ++j) bbase += bs[j];
    const int i = blockIdx.x * SCAN_BS + tid;
    if (i < N_NODES) {
        const int o = offs[i] + bbase;
        offs[i] = o;
        cursor[i] = o;
    }
    if (blockIdx.x == NBLK_SCAN - 1 && tid == SCAN_BS - 1)
        offs[N_NODES] = bbase + bs[NBLK_SCAN - 1];
}

// ============================ MFMA edge MLP v3 ============================
// Round-10 verified body + occupancy push: Wt4 A-frags from global (L2), only
// W1t/Wt2/Wt3 staged (20KB), two-phase wxT copy-out through a 24KB alias window.

__global__ __launch_bounds__(512, 4)
void edge_mlp_mfma(const float* __restrict__ length,
                   const float* __restrict__ nf,
                   const int*   __restrict__ eidx,
                   int* __restrict__ cursor,
                   int* __restrict__ order,
                   const f16*   __restrict__ wimg,
                   f16* __restrict__ wx)
{
    __shared__ __align__(16) char s[EK_LDS];
    __shared__ int sendS[128];
    __shared__ int rankS[128];

    const int tid = threadIdx.x;
    const int ebase = blockIdx.x << 7;

    // ---- stage W1t/Wt2/Wt3 only: image bytes [24576,45056) -> s[0,20480) ----
    {
        const uint4* src = (const uint4*)wimg + 1536;   // 24576/16
        uint4* dst = (uint4*)s;
#pragma unroll
        for (int i = 0; i < 3; ++i) {
            const int c = i * 512 + tid;
            if (c < 1280) dst[c] = src[c];
        }
    }
    // ---- stage h0 (128 x 32 f16, k>=8 zeroed), swizzle mask 3; fused scatter ----
    if (tid < 128) {
        const int e = tid;
        const int eg = ebase + e;
        const float4 q0 = *(const float4*)&length[(size_t)eg * 8];
        const float4 q1 = *(const float4*)&length[(size_t)eg * 8 + 4];
        f16x8 h;
        h[0] = (f16)q0.x; h[1] = (f16)q0.y; h[2] = (f16)q0.z; h[3] = (f16)q0.w;
        h[4] = (f16)q1.x; h[5] = (f16)q1.y; h[6] = (f16)q1.z; h[7] = (f16)q1.w;
        *(f16x8*)(s + EK_H0 + e * 64 + ((0 ^ (e & 3)) << 4)) = h;
        sendS[e] = eidx[eg];
        const int rcv = eidx[N_EDGES + eg];
        const int pos = atomicAdd(&cursor[rcv], 1);   // fused scatter
        order[pos] = eg;
        rankS[e] = pos;
    } else {
        const int idx = tid - 128;
        const int e = idx / 3, gz = 1 + idx - (idx / 3) * 3;
        uint4 z; z.x = 0; z.y = 0; z.z = 0; z.w = 0;
        *(uint4*)(s + EK_H0 + e * 64 + ((gz ^ (e & 3)) << 4)) = z;
    }
    __syncthreads();

    const int lane = tid & 63, w = tid >> 6;
    const int eh = w >> 2, wm = w & 3;
    const int lm = lane & 15, lg = lane >> 4;
    const int mrow = wm * 16 + lm;
    const int r0 = lg << 2;
    const int eloc0 = eh << 6;

    const f32x4 zacc = {0.f, 0.f, 0.f, 0.f};
    f32x4 acc[4];

    // L1
    {
        const f16x8 a = *(const f16x8*)(s + EK_W1T + mrow * 64 + ((lg ^ (mrow & 3)) << 4));
#pragma unroll
        for (int nt = 0; nt < 4; ++nt) {
            const int e = eloc0 + nt * 16 + lm;
            const f16x8 b = *(const f16x8*)(s + EK_H0 + e * 64 + ((lg ^ (e & 3)) << 4));
            acc[nt] = __builtin_amdgcn_mfma_f32_16x16x32_f16(a, b, zacc, 0, 0, 0);
        }
    }
    {
        const int c = wm * 16 + r0;
#pragma unroll
        for (int nt = 0; nt < 4; ++nt) {
            const int e = eloc0 + nt * 16 + lm;
            f16x4 pk;
            pk[0] = (f16)silu_f(acc[nt][0] * 0.35355339059f);
            pk[1] = (f16)silu_f(acc[nt][1] * 0.35355339059f);
            pk[2] = (f16)silu_f(acc[nt][2] * 0.35355339059f);
            pk[3] = (f16)silu_f(acc[nt][3] * 0.35355339059f);
            *(f16x4*)(s + EK_HT + e * 128 + (((c >> 3) ^ (e & 7)) << 4) + ((c & 7) << 1)) = pk;
        }
    }
    __syncthreads();

    // L2
#pragma unroll
    for (int nt = 0; nt < 4; ++nt) acc[nt] = zacc;
#pragma unroll
    for (int kh = 0; kh < 2; ++kh) {
        const int g = (kh << 2) + lg;
        const f16x8 a = *(const f16x8*)(s + EK_WT2 + mrow * 128 + ((g ^ (mrow & 7)) << 4));
#pragma unroll
        for (int nt = 0; nt < 4; ++nt) {
            const int e = eloc0 + nt * 16 + lm;
            const f16x8 b = *(const f16x8*)(s + EK_HT + e * 128 + ((g ^ (e & 7)) << 4));
            acc[nt] = __builtin_amdgcn_mfma_f32_16x16x32_f16(a, b, acc[nt], 0, 0, 0);
        }
    }
    __syncthreads();
    {
        const int c = wm * 16 + r0;
#pragma unroll
        for (int nt = 0; nt < 4; ++nt) {
            const int e = eloc0 + nt * 16 + lm;
            f16x4 pk;
            pk[0] = (f16)silu_f(acc[nt][0] * 0.125f);
            pk[1] = (f16)silu_f(acc[nt][1] * 0.125f);
            pk[2] = (f16)silu_f(acc[nt][2] * 0.125f);
            pk[3] = (f16)silu_f(acc[nt][3] * 0.125f);
            *(f16x4*)(s + EK_HT + e * 128 + (((c >> 3) ^ (e & 7)) << 4) + ((c & 7) << 1)) = pk;
        }
    }
    __syncthreads();

    // L3
#pragma unroll
    for (int nt = 0; nt < 4; ++nt) acc[nt] = zacc;
#pragma unroll
    for (int kh = 0; kh < 2; ++kh) {
        const int g = (kh << 2) + lg;
        const f16x8 a = *(const f16x8*)(s + EK_WT3 + mrow * 128 + ((g ^ (mrow & 7)) << 4));
#pragma unroll
        for (int nt = 0; nt < 4; ++nt) {
            const int e = eloc0 + nt * 16 + lm;
            const f16x8 b = *(const f16x8*)(s + EK_HT + e * 128 + ((g ^ (e & 7)) << 4));
            acc[nt] = __builtin_amdgcn_mfma_f32_16x16x32_f16(a, b, acc[nt], 0, 0, 0);
        }
    }
    __syncthreads();
    {
        const int c = wm * 16 + r0;
#pragma unroll
        for (int nt = 0; nt < 4; ++nt) {
            const int e = eloc0 + nt * 16 + lm;
            f16x4 pk;
            pk[0] = (f16)silu_f(acc[nt][0] * 0.125f);
            pk[1] = (f16)silu_f(acc[nt][1] * 0.125f);
            pk[2] = (f16)silu_f(acc[nt][2] * 0.125f);
            pk[3] = (f16)silu_f(acc[nt][3] * 0.125f);
            *(f16x4*)(s + EK_HT + e * 128 + (((c >> 3) ^ (e & 7)) << 4) + ((c & 7) << 1)) = pk;
        }
    }
    __syncthreads();

    // L4: A-frags (Wt4) straight from the L2-resident image
    f32x4 acc4[3][4];
#pragma unroll
    for (int p = 0; p < 3; ++p)
#pragma unroll
        for (int nt = 0; nt < 4; ++nt) acc4[p][nt] = zacc;
#pragma unroll
    for (int kh = 0; kh < 2; ++kh) {
        const int g = (kh << 2) + lg;
        f16x8 ap[3];
#pragma unroll
        for (int p = 0; p < 3; ++p) {
            const int m4 = p * 64 + mrow;
            ap[p] = *(const f16x8*)((const char*)wimg + IMG_WT4_B + m4 * 128 + ((g ^ (m4 & 7)) << 4));
        }
#pragma unroll
        for (int nt = 0; nt < 4; ++nt) {
            const int e = eloc0 + nt * 16 + lm;
            const f16x8 b = *(const f16x8*)(s + EK_HT + e * 128 + ((g ^ (e & 7)) << 4));
#pragma unroll
            for (int p = 0; p < 3; ++p)
                acc4[p][nt] = __builtin_amdgcn_mfma_f32_16x16x32_f16(ap[p], b, acc4[p][nt], 0, 0, 0);
        }
    }
    // NOTE: no barrier needed before eh==0 wxT writes — wxT window [0,24576)
    // is W1t/Wt2/Wt3/H0 (all dead since the post-L3 barrier); L4 reads only
    // HT (28672+) and global.

    // ---- two-phase wxT copy-out (64 edges / 24KB window per phase) ----
#pragma unroll
    for (int ph = 0; ph < 2; ++ph) {
        if (eh == ph) {
#pragma unroll
            for (int nt = 0; nt < 4; ++nt) {
                const int e = eloc0 + nt * 16 + lm;     // global-local edge id
                const int el = e - ph * 64;             // window-local (0..63)
                const int snd = sendS[e];
                const float4 nf4 = *(const float4*)&nf[(size_t)snd * 64 + wm * 16 + r0];
#pragma unroll
                for (int p = 0; p < 3; ++p) {
                    const int c = p * 64 + wm * 16 + r0;
                    f16x4 pk;
                    pk[0] = (f16)(acc4[p][nt][0] * 0.125f * nf4.x);
                    pk[1] = (f16)(acc4[p][nt][1] * 0.125f * nf4.y);
                    pk[2] = (f16)(acc4[p][nt][2] * 0.125f * nf4.z);
                    pk[3] = (f16)(acc4[p][nt][3] * 0.125f * nf4.w);
                    *(f16x4*)(s + EK_WXT + el * 384 + (((c >> 3) ^ (el & 7)) << 4) + ((c & 7) << 1)) = pk;
                }
            }
        }
        __syncthreads();
        // all 512 threads copy out this phase's 64 edges: 1536 uint4 chunks
#pragma unroll
        for (int it = 0; it < 3; ++it) {
            const int chunk = it * 512 + tid;
            const int el = chunk / 24, g = chunk - el * 24;
            const uint4 v = *(const uint4*)(s + EK_WXT + el * 384 + ((g ^ (el & 7)) << 4));
            *(uint4*)((char*)wx + (size_t)rankS[el + ph * 64] * 384 + g * 16) = v;
        }
        __syncthreads();
    }
}

// ============================ gather: streaming wx -> mT fp16 [m][n][u] ============================
// (round-8 verified; 20000 waves of TLP — do NOT fuse into node_mfma, round-9
// showed that collapses parallelism 16x and regresses 2.5x)

__global__ __launch_bounds__(256, 8)
void gather_kernel(const __half* __restrict__ wx,     // E x 192 f16, receiver-sorted
                   const float* __restrict__ ea,      // E x 9
                   const int* __restrict__ offs,      // N+1
                   const int* __restrict__ order,     // E (for ea lookup only)
                   f16* __restrict__ mT)              // 9 x NPAD x 64
{
    const int tid = threadIdx.x;
    const int wid = tid >> 6;
    const int v   = tid & 63;
    const int n   = (blockIdx.x << 2) + wid;
    const int beg = offs[n];
    const int end = offs[n + 1];

    float a0 = 0.f, a1[3] = {0.f, 0.f, 0.f}, a2[5] = {0.f, 0.f, 0.f, 0.f, 0.f};
    int k = beg;
    for (; k + 2 <= end; k += 2) {
        const int eA = __builtin_amdgcn_readfirstlane(order[k]);
        const int eB = __builtin_amdgcn_readfirstlane(order[k + 1]);
        const __half* wrA = wx + (size_t)k * 192;         // sequential
        const __half* wrB = wx + (size_t)(k + 1) * 192;
        const float xA0 = __half2float(wrA[v]);
        const float xA1 = __half2float(wrA[64 + v]);
        const float xA2 = __half2float(wrA[128 + v]);
        const float xB0 = __half2float(wrB[v]);
        const float xB1 = __half2float(wrB[64 + v]);
        const float xB2 = __half2float(wrB[128 + v]);
        const float* yA = ea + (size_t)eA * 9;
        const float* yB = ea + (size_t)eB * 9;
        a0 += xA0 * yA[0] + xB0 * yB[0];
#pragma unroll
        for (int m = 0; m < 3; ++m) a1[m] += xA1 * yA[1 + m] + xB1 * yB[1 + m];
#pragma unroll
        for (int m = 0; m < 5; ++m) a2[m] += xA2 * yA[4 + m] + xB2 * yB[4 + m];
    }
    if (k < end) {
        const int e = __builtin_amdgcn_readfirstlane(order[k]);
        const __half* wr = wx + (size_t)k * 192;
        const float x0 = __half2float(wr[v]);
        const float x1 = __half2float(wr[64 + v]);
        const float x2 = __half2float(wr[128 + v]);
        const float* y = ea + (size_t)e * 9;
        a0 += x0 * y[0];
#pragma unroll
        for (int m = 0; m < 3; ++m) a1[m] += x1 * y[1 + m];
#pragma unroll
        for (int m = 0; m < 5; ++m) a2[m] += x2 * y[4 + m];
    }

    f16* base = mT + (size_t)n * 64 + v;
    base[0] = (f16)a0;
#pragma unroll
    for (int m = 0; m < 3; ++m) base[(size_t)(1 + m) * MT_S] = (f16)a1[m];
#pragma unroll
    for (int m = 0; m < 5; ++m) base[(size_t)(4 + m) * MT_S] = (f16)a2[m];
}

// ============================ MFMA node transform v2 (round-7/8 verified) ============================

__global__ __launch_bounds__(256, 2)
void node_mfma(const f16* __restrict__ wimg,
               const f16* __restrict__ mT,      // 9 x NPAD x 64
               const float* __restrict__ nf,    // N x 64
               const float* __restrict__ na,    // N x 4
               float* __restrict__ out)
{
    __shared__ __align__(16) f16  mst[9 * 16 * 64];   // [m][r][u] swizzled
    __shared__ __align__(16) f16  nft[16 * 64];
    __shared__ __align__(16) float nas[256];
    __shared__ __align__(16) float outb[16 * 580];

    const int tid = threadIdx.x;
    const int lane = tid & 63, w = tid >> 6;
    const int lm = lane & 15, lg = lane >> 4;
    const int r0 = lg << 2;
    const int n0 = blockIdx.x << 6;

    const f16* wlT  = wimg + OFF_WLT;
    const f16* wscT = wimg + OFF_WSCT;
    f16x8 wl[3][2];
#pragma unroll
    for (int l = 0; l < 3; ++l)
#pragma unroll
        for (int kk = 0; kk < 2; ++kk)
            wl[l][kk] = *(const f16x8*)(wlT + ((l << 6) + (w << 4) + lm) * 64 + (kk << 5) + (lg << 3));
    f16x8 wsc[8];
#pragma unroll
    for (int kg = 0; kg < 8; ++kg)
        wsc[kg] = *(const f16x8*)(wscT + ((w << 4) + lm) * 256 + (kg << 5) + (lg << 3));

    {
        const int n = n0 + (tid >> 2);
        nas[tid] = (n < N_NODES) ? na[(size_t)n * 4 + (tid & 3)] : 0.f;
    }

    const f32x4 zacc = {0.f, 0.f, 0.f, 0.f};

    for (int nt = 0; nt < 4; ++nt) {
        const int ng = n0 + (nt << 4);
        __syncthreads();

#pragma unroll
        for (int it = 0; it < 5; ++it) {
            const int c = it * 256 + tid;
            if (c < 1152) {
                const int m = c >> 7, rem = c & 127, r = rem >> 3, g = rem & 7;
                const uint4 v = *(const uint4*)(mT + (size_t)m * MT_S + (size_t)(ng + r) * 64 + (g << 3));
                *(uint4*)(&mst[m * 1024 + r * 64 + ((g ^ (r & 7)) << 3)]) = v;
            }
        }
        {
            const int r = tid >> 4, c4 = (tid & 15) << 2;
            const int n = ng + r;
            float4 v4;
            if (n < N_NODES) v4 = *(const float4*)&nf[(size_t)n * 64 + c4];
            else { v4.x = 0.f; v4.y = 0.f; v4.z = 0.f; v4.w = 0.f; }
            f16x4 h;
            h[0] = (f16)v4.x; h[1] = (f16)v4.y; h[2] = (f16)v4.z; h[3] = (f16)v4.w;
            const int g = c4 >> 3;
            *(f16x4*)&nft[r * 64 + ((g ^ (r & 7)) << 3) + (c4 & 7)] = h;
        }
        __syncthreads();

#pragma unroll
        for (int m = 0; m < 9; ++m) {
            const int l = (m == 0) ? 0 : ((m < 4) ? 1 : 2);
            f32x4 acc = zacc;
#pragma unroll
            for (int kk = 0; kk < 2; ++kk) {
                const int g = (kk << 2) + lg;
                const f16x8 b = *(const f16x8*)&mst[m * 1024 + lm * 64 + ((g ^ (lm & 7)) << 3)];
                acc = __builtin_amdgcn_mfma_f32_16x16x32_f16(wl[l][kk], b, acc, 0, 0, 0);
            }
#pragma unroll
            for (int i = 0; i < 4; ++i)
                outb[lm * 580 + ((w << 4) + r0 + i) * 9 + m] = acc[i] * 0.125f;
        }
        __syncthreads();

#pragma unroll
        for (int it = 0; it < 9; ++it) {
            const int c = it * 256 + tid;
            const int r = c / 144, q = c - r * 144;
            const int n = ng + r;
            if (n < N_NODES) {
                const float4 v = *(const float4*)&outb[r * 580 + (q << 2)];
                *(float4*)&out[(size_t)n * 576 + (q << 2)] = v;
            }
        }
        __syncthreads();

        {
            const float4 na4 = *(const float4*)&nas[((nt << 4) + lm) << 2];
            const float* nap = (const float*)&na4;
            f32x4 sacc = zacc;
#pragma unroll
            for (int kg = 0; kg < 8; ++kg) {
                const int g = ((kg & 1) << 2) + lg;
                f16x8 q = *(const f16x8*)&nft[lm * 64 + ((g ^ (lm & 7)) << 3)];
                const f16 sa = (f16)nap[kg >> 1];
                q = q * sa;
                sacc = __builtin_amdgcn_mfma_f32_16x16x32_f16(wsc[kg], q, sacc, 0, 0, 0);
            }
#pragma unroll
            for (int i = 0; i < 4; ++i)
                outb[lm * 580 + (w << 4) + r0 + i] = sacc[i] * 0.0625f;
        }
        __syncthreads();

        {
            const int r = tid >> 4, q = tid & 15;
            const int n = ng + r;
            if (n < N_NODES)
                *(float4*)&out[(size_t)MSG_OFF + (size_t)n * 576 + (q << 2)] =
                    *(const float4*)&outb[r * 580 + (q << 2)];
        }
        float4 z4; z4.x = 0.f; z4.y = 0.f; z4.z = 0.f; z4.w = 0.f;
#pragma unroll
        for (int it = 0; it < 8; ++it) {
            const int c = it * 256 + tid;
            const int r = c >> 7, q = c & 127;
            const int n = ng + r;
            if (n < N_NODES)
                *(float4*)&out[(size_t)MSG_OFF + (size_t)n * 576 + 64 + (q << 2)] = z4;
        }
    }
}

// ============================ fallback (atomic, fp32) path ============================

__device__ __forceinline__ void layer_accum(const float* src, const float* __restrict__ W,
                                            float a2[4][4], int c0, int e0) {
#pragma unroll
    for (int i = 0; i < 4; ++i)
#pragma unroll
        for (int j = 0; j < 4; ++j) a2[i][j] = 0.f;
#pragma unroll 8
    for (int u = 0; u < 64; ++u) {
        const float4 h4 = *(const float4*)&src[(u << 6) + e0];
        const float4 w4 = *(const float4*)&W[(u << 6) + c0];
        const float hv[4] = {h4.x, h4.y, h4.z, h4.w};
        const float wv[4] = {w4.x, w4.y, w4.z, w4.w};
#pragma unroll
        for (int i = 0; i < 4; ++i)
#pragma unroll
            for (int j = 0; j < 4; ++j) a2[i][j] += wv[i] * hv[j];
    }
}

__device__ __forceinline__ void layer_store(float* dst, const float a2[4][4],
                                            float scale, int c0, int e0) {
#pragma unroll
    for (int i = 0; i < 4; ++i) {
        float4 v;
        v.x = silu_f(a2[i][0] * scale);
        v.y = silu_f(a2[i][1] * scale);
        v.z = silu_f(a2[i][2] * scale);
        v.w = silu_f(a2[i][3] * scale);
        *(float4*)&dst[((c0 + i) << 6) + e0] = v;
    }
}

__global__ __launch_bounds__(256, 4)
void edge_kernel_atomic(const float* __restrict__ length,
                        const float* __restrict__ nf,
                        const float* __restrict__ ea,
                        const float* __restrict__ W1,
                        const float* __restrict__ W2,
                        const float* __restrict__ W3,
                        const float* __restrict__ W4,
                        const int*   __restrict__ eidx,
                        float* __restrict__ msg)
{
    __shared__ float buf[4096];
    __shared__ float lenS[512];
    __shared__ float Ys[576];
    __shared__ int   sendS[64];
    __shared__ int   recvS[64];

    const int tid = threadIdx.x;
    const int tx = tid & 15;
    const int ty = tid >> 4;
    const int c0 = tx << 2;
    const int e0 = ty << 2;
    const int ebase = blockIdx.x << 6;

    for (int i = tid; i < 512; i += 256) {
        const int e = i >> 3, k = i & 7;
        lenS[(k << 6) + e] = length[((ebase + e) << 3) + k];
    }
    for (int i = tid; i < 576; i += 256) Ys[i] = ea[ebase * 9 + i];
    if (tid < 64) {
        sendS[tid] = eidx[ebase + tid];
        recvS[tid] = eidx[N_EDGES + ebase + tid];
    }
    __syncthreads();

    {
        float a2[4][4];
#pragma unroll
        for (int i = 0; i < 4; ++i)
#pragma unroll
            for (int j = 0; j < 4; ++j) a2[i][j] = 0.f;
#pragma unroll
        for (int k = 0; k < 8; ++k) {
            const float4 h4 = *(const float4*)&lenS[(k << 6) + e0];
            const float4 w4 = *(const float4*)&W1[(k << 6) + c0];
            const float hv[4] = {h4.x, h4.y, h4.z, h4.w};
            const float wv[4] = {w4.x, w4.y, w4.z, w4.w};
#pragma unroll
            for (int i = 0; i < 4; ++i)
#pragma unroll
                for (int j = 0; j < 4; ++j) a2[i][j] += wv[i] * hv[j];
        }
        layer_store(buf, a2, 0.35355339059327373f, c0, e0);
    }
    __syncthreads();
    {
        float a2[4][4];
        layer_accum(buf, W2, a2, c0, e0);
        __syncthreads();
        layer_store(buf, a2, 0.125f, c0, e0);
    }
    __syncthreads();
    {
        float a2[4][4];
        layer_accum(buf, W3, a2, c0, e0);
        __syncthreads();
        layer_store(buf, a2, 0.125f, c0, e0);
    }
    __syncthreads();

    float wacc[3][4][4];
#pragma unroll
    for (int l = 0; l < 3; ++l)
#pragma unroll
        for (int i = 0; i < 4; ++i)
#pragma unroll
            for (int j = 0; j < 4; ++j) wacc[l][i][j] = 0.f;
#pragma unroll 4
    for (int u = 0; u < 64; ++u) {
        const float4 h4 = *(const float4*)&buf[(u << 6) + e0];
        const float hv[4] = {h4.x, h4.y, h4.z, h4.w};
#pragma unroll
        for (int l = 0; l < 3; ++l) {
            const float4 w4 = *(const float4*)&W4[u * 192 + (l << 6) + c0];
            const float wv[4] = {w4.x, w4.y, w4.z, w4.w};
#pragma unroll
            for (int i = 0; i < 4; ++i)
#pragma unroll
                for (int j = 0; j < 4; ++j) wacc[l][i][j] += wv[i] * hv[j];
        }
    }

#pragma unroll
    for (int j = 0; j < 4; ++j) {
        const int e = e0 + j;
        const int snd = sendS[e];
        const int rcv = recvS[e];
        const float4 nf4 = *(const float4*)&nf[(snd << 6) + c0];
        const float nfv[4] = {nf4.x, nf4.y, nf4.z, nf4.w};
        float* mrow = msg + rcv * MSG_ROW;
        const float y0 = Ys[e * 9 + 0];
        float y1[3], y2[5];
#pragma unroll
        for (int m = 0; m < 3; ++m) y1[m] = Ys[e * 9 + 1 + m];
#pragma unroll
        for (int m = 0; m < 5; ++m) y2[m] = Ys[e * 9 + 4 + m];
#pragma unroll
        for (int i = 0; i < 4; ++i) {
            const int c = c0 + i;
            const float wx0 = wacc[0][i][j] * 0.125f * nfv[i];
            const float wx1 = wacc[1][i][j] * 0.125f * nfv[i];
            const float wx2 = wacc[2][i][j] * 0.125f * nfv[i];
            atomicAdd(&mrow[c], wx0 * y0);
#pragma unroll
            for (int m = 0; m < 3; ++m) atomicAdd(&mrow[64 + c * 3 + m], wx1 * y1[m]);
#pragma unroll
            for (int m = 0; m < 5; ++m) atomicAdd(&mrow[256 + c * 5 + m], wx2 * y2[m]);
        }
    }
}

__global__ __launch_bounds__(256, 4)
void node_kernel(const float* __restrict__ nf,
                 const float* __restrict__ na,
                 const float* __restrict__ Wl,
                 const float* __restrict__ Wsc,
                 float* __restrict__ out)
{
    __shared__ float ms[4][576];
    __shared__ float fs[4][64];
    const int tid = threadIdx.x;
    const int wid = tid >> 6;
    const int v   = tid & 63;
    const int n   = (blockIdx.x << 2) + wid;
    const float* msg = out + MSG_OFF;

#pragma unroll
    for (int j = 0; j < 9; ++j)
        ms[wid][(j << 6) + v] = msg[n * MSG_ROW + (j << 6) + v];
    fs[wid][v] = nf[(n << 6) + v];
    __syncthreads();

    float o9[9];
#pragma unroll
    for (int j = 0; j < 9; ++j) o9[j] = 0.f;
    const float* m0 = &ms[wid][0];
    const float* m1 = &ms[wid][64];
    const float* m2 = &ms[wid][256];

#pragma unroll 8
    for (int u = 0; u < 64; ++u) {
        const float w0 = Wl[(u << 6) + v];
        const float w1 = Wl[4096 + (u << 6) + v];
        const float w2 = Wl[8192 + (u << 6) + v];
        o9[0] += m0[u] * w0;
        o9[1] += m1[u * 3 + 0] * w1;
        o9[2] += m1[u * 3 + 1] * w1;
        o9[3] += m1[u * 3 + 2] * w1;
        o9[4] += m2[u * 5 + 0] * w2;
        o9[5] += m2[u * 5 + 1] * w2;
        o9[6] += m2[u * 5 + 2] * w2;
        o9[7] += m2[u * 5 + 3] * w2;
        o9[8] += m2[u * 5 + 4] * w2;
    }
#pragma unroll
    for (int j = 0; j < 9; ++j) out[n * MSG_ROW + v * 9 + j] = o9[j] * 0.125f;

    const float b0 = na[(n << 2) + 0];
    const float b1 = na[(n << 2) + 1];
    const float b2 = na[(n << 2) + 2];
    const float b3 = na[(n << 2) + 3];
    float sacc = 0.f;
#pragma unroll 8
    for (int u = 0; u < 64; ++u) {
        const float f = fs[wid][u];
        sacc += f * (b0 * Wsc[(u << 6) + v] + b1 * Wsc[4096 + (u << 6) + v] +
                     b2 * Wsc[8192 + (u << 6) + v] + b3 * Wsc[12288 + (u << 6) + v]);
    }
    float* scrow = out + MSG_OFF + n * MSG_ROW;
    scrow[v] = sacc * 0.0625f;
#pragma unroll
    for (int j = 1; j < 9; ++j) scrow[(j << 6) + v] = 0.f;
}

extern "C" void kernel_launch(void* const* d_in, const int* in_sizes, int n_in,
                              void* d_out, int out_size, void* d_ws, size_t ws_size,
                              hipStream_t stream) {
    const float* length = (const float*)d_in[0];
    const float* nfeat  = (const float*)d_in[1];
    const float* nattr  = (const float*)d_in[2];
    const float* eattr  = (const float*)d_in[3];
    const float* W1     = (const float*)d_in[4];
    const float* W2     = (const float*)d_in[5];
    const float* W3     = (const float*)d_in[6];
    const float* W4     = (const float*)d_in[7];
    const float* Wl     = (const float*)d_in[8];
    const float* Wsc    = (const float*)d_in[9];
    const int*   eidx   = (const int*)d_in[10];
    float* out = (float*)d_out;

    // ws: wimg(102400B) | wx[E*192 f16] | mT[9*NPAD*64 f16] | counts|offs|cursor|order|bsum
    f16*    wimg   = (f16*)d_ws;
    __half* wx     = (__half*)((char*)d_ws + WIMG_BYTES);
    f16*    mT     = (f16*)((char*)d_ws + WIMG_BYTES + (size_t)N_EDGES * 192 * 2);
    int*   counts  = (int*)((char*)mT + (size_t)9 * MT_S * 2);
    int*   offsets = counts + N_NODES;
    int*   cursor  = offsets + N_NODES + 1;
    int*   order   = cursor + N_NODES;
    int*   bsum    = order + N_EDGES;
    const size_t need = WIMG_BYTES + (size_t)N_EDGES * 192 * 2 + (size_t)9 * MT_S * 2 +
                        (size_t)(N_NODES * 3 + 1 + N_EDGES + 128) * 4;

    if (ws_size >= need) {
        hipMemsetAsync(counts, 0, N_NODES * sizeof(int), stream);
        pre_kernel<<<WIMG_BLOCKS + N_EDGES / 256, 256, 0, stream>>>(W1, W2, W3, W4, Wl, Wsc,
                                                                    wimg, eidx, counts);
        scan1_kernel<<<NBLK_SCAN, SCAN_BS, 0, stream>>>(counts, offsets, bsum);
        scan3_kernel<<<NBLK_SCAN, SCAN_BS, 0, stream>>>(offsets, bsum, cursor);
        edge_mlp_mfma<<<N_EDGES / 128, 512, 0, stream>>>(length, nfeat, eidx, cursor, order,
                                                         wimg, (f16*)wx);
        gather_kernel<<<N_NODES / 4, 256, 0, stream>>>(wx, eattr, offsets, order, mT);
        node_mfma<<<NPAD / 64, 256, 0, stream>>>(wimg, mT, nfeat, nattr, out);
    } else {
        hipMemsetAsync(out + MSG_OFF, 0, (size_t)N_NODES * MSG_ROW * sizeof(float), stream);
        edge_kernel_atomic<<<N_EDGES / 64, 256, 0, stream>>>(length, nfeat, eattr,
                                                             W1, W2, W3, W4, eidx,
                                                             out + MSG_OFF);
        node_kernel<<<N_NODES / 4, 256, 0, stream>>>(nfeat, nattr, Wl, Wsc, out);
    }
}

// Round 12
// 152.433 us; speedup vs baseline: 1.0173x; 1.0173x over previous
//
#include <hip/hip_runtime.h>
#include <hip/hip_fp16.h>

#define N_NODES 20000
#define N_EDGES 320000
#define MSG_ROW 576
#define MSG_OFF 11520000   // N_NODES * 576 : sc region of d_out (fallback msg buffer)
#define SCAN_BS 256
#define NBLK_SCAN ((N_NODES + SCAN_BS - 1) / SCAN_BS)   // 79
#define NPAD 20032         // 313 * 64
#define MT_S (NPAD * 64)   // halfs per m-slice of mT

typedef _Float16 f16;
typedef _Float16 f16x4 __attribute__((ext_vector_type(4)));
typedef _Float16 f16x8 __attribute__((ext_vector_type(8)));
typedef float f32x4 __attribute__((ext_vector_type(4)));

// weight image (f16 elems): [Wt4 12288 | W1t 2048 | Wt2 4096 | Wt3 4096 | WlT 12288 | WscT 16384]
// image BYTE offsets: Wt4 [0,24576) | W1t [24576,28672) | Wt2 [28672,36864) | Wt3 [36864,45056)
#define IMG_WT4_B 0
#define IMG_W1T_B 24576
#define IMG_WT23_B 28672
#define OFF_WLT  22528   // f16 index
#define OFF_WSCT 34816
#define WIMG_HALF 51200
#define WIMG_BYTES 102400
#define WIMG_BLOCKS 200  // 200*256 = 51200

// edge kernel LDS (bytes) — round-12: only Wt2/Wt3 staged; H0 eliminated (L1 B
// direct from length: only lg==0 lanes carry data since W1t is zero-padded k>=8);
// W1t/Wt4 A-frags from L2-resident image. 46080 -> 33792 B.
#define EK_WT2 0         // 8192
#define EK_WT3 8192      // 8192
#define EK_HT  16384     // 16384, [16384,32768)
#define EK_LDS 32768
#define EK_WXT 0         // 64 edges x 384 B = 24576; overlaps Wt2/Wt3 (dead post-L3)
                         // and HT rows 0..63 (needs one post-L4 barrier)

__device__ __forceinline__ float silu_f(float x) {
    return x * (1.0f / (1.0f + __expf(-x)));
}

// ============================ pre-kernel: weight image + histogram ============================

__global__ __launch_bounds__(256)
void pre_kernel(const float* __restrict__ W1, const float* __restrict__ W2,
                const float* __restrict__ W3, const float* __restrict__ W4,
                const float* __restrict__ Wl, const float* __restrict__ Wsc,
                f16* __restrict__ img,
                const int* __restrict__ eidx, int* __restrict__ counts) {
    const int b = blockIdx.x;
    if (b >= WIMG_BLOCKS) {
        const int e = (b - WIMG_BLOCKS) * 256 + threadIdx.x;
        if (e < N_EDGES) atomicAdd(&counts[eidx[N_EDGES + e]], 1);
        return;
    }
    const int p = b * 256 + threadIdx.x;
    float v;
    if (p < 12288) {                         // Wt4 [192][64] swizzled
        const int m = p >> 6, rem = p & 63, g = rem >> 3, j = rem & 7;
        const int k = ((g ^ (m & 7)) << 3) | j;
        v = W4[k * 192 + m];
    } else if (p < 14336) {                  // W1t [64][32], k>=8 -> 0
        const int q = p - 12288;
        const int m = q >> 5, rem = q & 31, g = rem >> 3, j = rem & 7;
        const int k = ((g ^ (m & 3)) << 3) | j;
        v = (k < 8) ? W1[k * 64 + m] : 0.f;
    } else if (p < 18432) {                  // Wt2 [64][64]
        const int q = p - 14336;
        const int m = q >> 6, rem = q & 63, g = rem >> 3, j = rem & 7;
        const int k = ((g ^ (m & 7)) << 3) | j;
        v = W2[k * 64 + m];
    } else if (p < 22528) {                  // Wt3 [64][64]
        const int q = p - 18432;
        const int m = q >> 6, rem = q & 63, g = rem >> 3, j = rem & 7;
        const int k = ((g ^ (m & 7)) << 3) | j;
        v = W3[k * 64 + m];
    } else if (p < OFF_WSCT) {               // WlT [l][v][u] linear (register frags)
        const int q = p - OFF_WLT;
        const int l = q >> 12, r = q & 4095, vv = r >> 6, u = r & 63;
        v = Wl[(l * 64 + u) * 64 + vv];
    } else {                                 // WscT [w][a*64+u] linear
        const int q = p - OFF_WSCT;
        const int ww = q >> 8, kk = q & 255, a = kk >> 6, u = kk & 63;
        v = Wsc[(a * 64 + u) * 64 + ww];
    }
    img[p] = (f16)v;
}

// ============================ CSR build (2 kernels) ============================

__global__ __launch_bounds__(SCAN_BS)
void scan1_kernel(const int* __restrict__ counts, int* __restrict__ offs,
                  int* __restrict__ bsum) {
    __shared__ int sm[SCAN_BS];
    const int tid = threadIdx.x;
    const int i = blockIdx.x * SCAN_BS + tid;
    const int v = (i < N_NODES) ? counts[i] : 0;
    sm[tid] = v;
    __syncthreads();
#pragma unroll
    for (int off = 1; off < SCAN_BS; off <<= 1) {
        const int t = (tid >= off) ? sm[tid - off] : 0;
        __syncthreads();
        sm[tid] += t;
        __syncthreads();
    }
    if (i < N_NODES) offs[i] = sm[tid] - v;          // block-local exclusive
    if (tid == SCAN_BS - 1) bsum[blockIdx.x] = sm[tid];
}

__global__ __launch_bounds__(SCAN_BS)
void scan3_kernel(int* __restrict__ offs, const int* __restrict__ bsum,
                  int* __restrict__ cursor) {
    __shared__ int bs[NBLK_SCAN];
    const int tid = threadIdx.x;
    if (tid < NBLK_SCAN) bs[tid] = bsum[tid];
    __syncthreads();
    int bbase = 0;
    for (int j = 0; j < blockIdx.x; ++j) bbase += bs[j];
    const int i = blockIdx.x * SCAN_BS + tid;
    if (i < N_NODES) {
        const int o = offs[i] + bbase;
        offs[i] = o;
        cursor[i] = o;
    }
    if (blockIdx.x == NBLK_SCAN - 1 && tid == SCAN_BS - 1)
        offs[N_NODES] = bbase + bs[NBLK_SCAN - 1];
}

// ============================ MFMA edge MLP v4 ============================

__global__ __launch_bounds__(512, 4)
void edge_mlp_mfma(const float* __restrict__ length,
                   const float* __restrict__ nf,
                   const int*   __restrict__ eidx,
                   int* __restrict__ cursor,
                   int* __restrict__ order,
                   const f16*   __restrict__ wimg,
                   f16* __restrict__ wx)
{
    __shared__ __align__(16) char s[EK_LDS];
    __shared__ int sendS[128];
    __shared__ int rankS[128];

    const int tid = threadIdx.x;
    const int ebase = blockIdx.x << 7;

    // ---- stage Wt2+Wt3: image bytes [28672,45056) -> s[0,16384), 1024 uint4 ----
    {
        const uint4* src = (const uint4*)((const char*)wimg + IMG_WT23_B);
        uint4* dst = (uint4*)s;
        dst[tid] = src[tid];
        dst[tid + 512] = src[tid + 512];
    }
    // ---- fused scatter (no h0 staging needed) ----
    if (tid < 128) {
        const int eg = ebase + tid;
        sendS[tid] = eidx[eg];
        const int rcv = eidx[N_EDGES + eg];
        const int pos = atomicAdd(&cursor[rcv], 1);
        order[pos] = eg;
        rankS[tid] = pos;
    }
    // NOTE: no barrier here — L1 reads no staged LDS; the post-L1 barrier
    // covers staging (Wt2/Wt3), sendS/rankS, and HT writes together.

    const int lane = tid & 63, w = tid >> 6;
    const int eh = w >> 2, wm = w & 3;
    const int lm = lane & 15, lg = lane >> 4;
    const int mrow = wm * 16 + lm;
    const int r0 = lg << 2;
    const int eloc0 = eh << 6;

    const f32x4 zacc = {0.f, 0.f, 0.f, 0.f};
    f32x4 acc[4];

    // ---- L1: A from global W1t (zero-padded k>=8); B direct from length.
    // Only lg==0 lanes carry real B data (A is 0 for k>=8 -> product 0; B must
    // be finite there, use 0). ----
    {
        const f16x8 a = *(const f16x8*)((const char*)wimg + IMG_W1T_B + mrow * 64 + ((lg ^ (mrow & 3)) << 4));
#pragma unroll
        for (int nt = 0; nt < 4; ++nt) {
            const int e = eloc0 + nt * 16 + lm;
            f16x8 b;
            if (lg == 0) {
                const float4 q0 = *(const float4*)&length[(size_t)(ebase + e) * 8];
                const float4 q1 = *(const float4*)&length[(size_t)(ebase + e) * 8 + 4];
                b[0] = (f16)q0.x; b[1] = (f16)q0.y; b[2] = (f16)q0.z; b[3] = (f16)q0.w;
                b[4] = (f16)q1.x; b[5] = (f16)q1.y; b[6] = (f16)q1.z; b[7] = (f16)q1.w;
            } else {
                b[0] = (f16)0.f; b[1] = (f16)0.f; b[2] = (f16)0.f; b[3] = (f16)0.f;
                b[4] = (f16)0.f; b[5] = (f16)0.f; b[6] = (f16)0.f; b[7] = (f16)0.f;
            }
            acc[nt] = __builtin_amdgcn_mfma_f32_16x16x32_f16(a, b, zacc, 0, 0, 0);
        }
    }
    {
        const int c = wm * 16 + r0;
#pragma unroll
        for (int nt = 0; nt < 4; ++nt) {
            const int e = eloc0 + nt * 16 + lm;
            f16x4 pk;
            pk[0] = (f16)silu_f(acc[nt][0] * 0.35355339059f);
            pk[1] = (f16)silu_f(acc[nt][1] * 0.35355339059f);
            pk[2] = (f16)silu_f(acc[nt][2] * 0.35355339059f);
            pk[3] = (f16)silu_f(acc[nt][3] * 0.35355339059f);
            *(f16x4*)(s + EK_HT + e * 128 + (((c >> 3) ^ (e & 7)) << 4) + ((c & 7) << 1)) = pk;
        }
    }
    __syncthreads();   // staging + sendS/rankS + HT(L1) all visible

    // ---- L2 ----
#pragma unroll
    for (int nt = 0; nt < 4; ++nt) acc[nt] = zacc;
#pragma unroll
    for (int kh = 0; kh < 2; ++kh) {
        const int g = (kh << 2) + lg;
        const f16x8 a = *(const f16x8*)(s + EK_WT2 + mrow * 128 + ((g ^ (mrow & 7)) << 4));
#pragma unroll
        for (int nt = 0; nt < 4; ++nt) {
            const int e = eloc0 + nt * 16 + lm;
            const f16x8 b = *(const f16x8*)(s + EK_HT + e * 128 + ((g ^ (e & 7)) << 4));
            acc[nt] = __builtin_amdgcn_mfma_f32_16x16x32_f16(a, b, acc[nt], 0, 0, 0);
        }
    }
    __syncthreads();
    {
        const int c = wm * 16 + r0;
#pragma unroll
        for (int nt = 0; nt < 4; ++nt) {
            const int e = eloc0 + nt * 16 + lm;
            f16x4 pk;
            pk[0] = (f16)silu_f(acc[nt][0] * 0.125f);
            pk[1] = (f16)silu_f(acc[nt][1] * 0.125f);
            pk[2] = (f16)silu_f(acc[nt][2] * 0.125f);
            pk[3] = (f16)silu_f(acc[nt][3] * 0.125f);
            *(f16x4*)(s + EK_HT + e * 128 + (((c >> 3) ^ (e & 7)) << 4) + ((c & 7) << 1)) = pk;
        }
    }
    __syncthreads();

    // ---- L3 ----
#pragma unroll
    for (int nt = 0; nt < 4; ++nt) acc[nt] = zacc;
#pragma unroll
    for (int kh = 0; kh < 2; ++kh) {
        const int g = (kh << 2) + lg;
        const f16x8 a = *(const f16x8*)(s + EK_WT3 + mrow * 128 + ((g ^ (mrow & 7)) << 4));
#pragma unroll
        for (int nt = 0; nt < 4; ++nt) {
            const int e = eloc0 + nt * 16 + lm;
            const f16x8 b = *(const f16x8*)(s + EK_HT + e * 128 + ((g ^ (e & 7)) << 4));
            acc[nt] = __builtin_amdgcn_mfma_f32_16x16x32_f16(a, b, acc[nt], 0, 0, 0);
        }
    }
    __syncthreads();
    {
        const int c = wm * 16 + r0;
#pragma unroll
        for (int nt = 0; nt < 4; ++nt) {
            const int e = eloc0 + nt * 16 + lm;
            f16x4 pk;
            pk[0] = (f16)silu_f(acc[nt][0] * 0.125f);
            pk[1] = (f16)silu_f(acc[nt][1] * 0.125f);
            pk[2] = (f16)silu_f(acc[nt][2] * 0.125f);
            pk[3] = (f16)silu_f(acc[nt][3] * 0.125f);
            *(f16x4*)(s + EK_HT + e * 128 + (((c >> 3) ^ (e & 7)) << 4) + ((c & 7) << 1)) = pk;
        }
    }
    __syncthreads();

    // ---- L4: A-frags (Wt4) from the L2-resident image ----
    f32x4 acc4[3][4];
#pragma unroll
    for (int p = 0; p < 3; ++p)
#pragma unroll
        for (int nt = 0; nt < 4; ++nt) acc4[p][nt] = zacc;
#pragma unroll
    for (int kh = 0; kh < 2; ++kh) {
        const int g = (kh << 2) + lg;
        f16x8 ap[3];
#pragma unroll
        for (int p = 0; p < 3; ++p) {
            const int m4 = p * 64 + mrow;
            ap[p] = *(const f16x8*)((const char*)wimg + IMG_WT4_B + m4 * 128 + ((g ^ (m4 & 7)) << 4));
        }
#pragma unroll
        for (int nt = 0; nt < 4; ++nt) {
            const int e = eloc0 + nt * 16 + lm;
            const f16x8 b = *(const f16x8*)(s + EK_HT + e * 128 + ((g ^ (e & 7)) << 4));
#pragma unroll
            for (int p = 0; p < 3; ++p)
                acc4[p][nt] = __builtin_amdgcn_mfma_f32_16x16x32_f16(ap[p], b, acc4[p][nt], 0, 0, 0);
        }
    }
    __syncthreads();   // wxT window [0,24576) overlaps HT rows 0..63 read by other eh==0 waves

    // ---- two-phase wxT copy-out (64 edges / 24KB window per phase) ----
#pragma unroll
    for (int ph = 0; ph < 2; ++ph) {
        if (eh == ph) {
#pragma unroll
            for (int nt = 0; nt < 4; ++nt) {
                const int e = eloc0 + nt * 16 + lm;     // block-local edge id
                const int el = e - ph * 64;             // window-local (0..63)
                const int snd = sendS[e];
                const float4 nf4 = *(const float4*)&nf[(size_t)snd * 64 + wm * 16 + r0];
#pragma unroll
                for (int p = 0; p < 3; ++p) {
                    const int c = p * 64 + wm * 16 + r0;
                    f16x4 pk;
                    pk[0] = (f16)(acc4[p][nt][0] * 0.125f * nf4.x);
                    pk[1] = (f16)(acc4[p][nt][1] * 0.125f * nf4.y);
                    pk[2] = (f16)(acc4[p][nt][2] * 0.125f * nf4.z);
                    pk[3] = (f16)(acc4[p][nt][3] * 0.125f * nf4.w);
                    *(f16x4*)(s + EK_WXT + el * 384 + (((c >> 3) ^ (el & 7)) << 4) + ((c & 7) << 1)) = pk;
                }
            }
        }
        __syncthreads();
        // all 512 threads copy out this phase's 64 edges: 1536 uint4 chunks
#pragma unroll
        for (int it = 0; it < 3; ++it) {
            const int chunk = it * 512 + tid;
            const int el = chunk / 24, g = chunk - el * 24;
            const uint4 v = *(const uint4*)(s + EK_WXT + el * 384 + ((g ^ (el & 7)) << 4));
            *(uint4*)((char*)wx + (size_t)rankS[el + ph * 64] * 384 + g * 16) = v;
        }
        __syncthreads();
    }
}

// ============================ gather: streaming wx -> mT fp16 [m][n][u] ============================
// (round-8 verified; 20000 waves of TLP — do NOT fuse into node_mfma, round-9
// showed that collapses parallelism 16x and regresses 2.5x)

__global__ __launch_bounds__(256, 8)
void gather_kernel(const __half* __restrict__ wx,     // E x 192 f16, receiver-sorted
                   const float* __restrict__ ea,      // E x 9
                   const int* __restrict__ offs,      // N+1
                   const int* __restrict__ order,     // E (for ea lookup only)
                   f16* __restrict__ mT)              // 9 x NPAD x 64
{
    const int tid = threadIdx.x;
    const int wid = tid >> 6;
    const int v   = tid & 63;
    const int n   = (blockIdx.x << 2) + wid;
    const int beg = offs[n];
    const int end = offs[n + 1];

    float a0 = 0.f, a1[3] = {0.f, 0.f, 0.f}, a2[5] = {0.f, 0.f, 0.f, 0.f, 0.f};
    int k = beg;
    for (; k + 2 <= end; k += 2) {
        const int eA = __builtin_amdgcn_readfirstlane(order[k]);
        const int eB = __builtin_amdgcn_readfirstlane(order[k + 1]);
        const __half* wrA = wx + (size_t)k * 192;         // sequential
        const __half* wrB = wx + (size_t)(k + 1) * 192;
        const float xA0 = __half2float(wrA[v]);
        const float xA1 = __half2float(wrA[64 + v]);
        const float xA2 = __half2float(wrA[128 + v]);
        const float xB0 = __half2float(wrB[v]);
        const float xB1 = __half2float(wrB[64 + v]);
        const float xB2 = __half2float(wrB[128 + v]);
        const float* yA = ea + (size_t)eA * 9;
        const float* yB = ea + (size_t)eB * 9;
        a0 += xA0 * yA[0] + xB0 * yB[0];
#pragma unroll
        for (int m = 0; m < 3; ++m) a1[m] += xA1 * yA[1 + m] + xB1 * yB[1 + m];
#pragma unroll
        for (int m = 0; m < 5; ++m) a2[m] += xA2 * yA[4 + m] + xB2 * yB[4 + m];
    }
    if (k < end) {
        const int e = __builtin_amdgcn_readfirstlane(order[k]);
        const __half* wr = wx + (size_t)k * 192;
        const float x0 = __half2float(wr[v]);
        const float x1 = __half2float(wr[64 + v]);
        const float x2 = __half2float(wr[128 + v]);
        const float* y = ea + (size_t)e * 9;
        a0 += x0 * y[0];
#pragma unroll
        for (int m = 0; m < 3; ++m) a1[m] += x1 * y[1 + m];
#pragma unroll
        for (int m = 0; m < 5; ++m) a2[m] += x2 * y[4 + m];
    }

    f16* base = mT + (size_t)n * 64 + v;
    base[0] = (f16)a0;
#pragma unroll
    for (int m = 0; m < 3; ++m) base[(size_t)(1 + m) * MT_S] = (f16)a1[m];
#pragma unroll
    for (int m = 0; m < 5; ++m) base[(size_t)(4 + m) * MT_S] = (f16)a2[m];
}

// ============================ MFMA node transform v2 (round-7/8 verified) ============================

__global__ __launch_bounds__(256, 2)
void node_mfma(const f16* __restrict__ wimg,
               const f16* __restrict__ mT,      // 9 x NPAD x 64
               const float* __restrict__ nf,    // N x 64
               const float* __restrict__ na,    // N x 4
               float* __restrict__ out)
{
    __shared__ __align__(16) f16  mst[9 * 16 * 64];   // [m][r][u] swizzled
    __shared__ __align__(16) f16  nft[16 * 64];
    __shared__ __align__(16) float nas[256];
    __shared__ __align__(16) float outb[16 * 580];

    const int tid = threadIdx.x;
    const int lane = tid & 63, w = tid >> 6;
    const int lm = lane & 15, lg = lane >> 4;
    const int r0 = lg << 2;
    const int n0 = blockIdx.x << 6;

    const f16* wlT  = wimg + OFF_WLT;
    const f16* wscT = wimg + OFF_WSCT;
    f16x8 wl[3][2];
#pragma unroll
    for (int l = 0; l < 3; ++l)
#pragma unroll
        for (int kk = 0; kk < 2; ++kk)
            wl[l][kk] = *(const f16x8*)(wlT + ((l << 6) + (w << 4) + lm) * 64 + (kk << 5) + (lg << 3));
    f16x8 wsc[8];
#pragma unroll
    for (int kg = 0; kg < 8; ++kg)
        wsc[kg] = *(const f16x8*)(wscT + ((w << 4) + lm) * 256 + (kg << 5) + (lg << 3));

    {
        const int n = n0 + (tid >> 2);
        nas[tid] = (n < N_NODES) ? na[(size_t)n * 4 + (tid & 3)] : 0.f;
    }

    const f32x4 zacc = {0.f, 0.f, 0.f, 0.f};

    for (int nt = 0; nt < 4; ++nt) {
        const int ng = n0 + (nt << 4);
        __syncthreads();

#pragma unroll
        for (int it = 0; it < 5; ++it) {
            const int c = it * 256 + tid;
            if (c < 1152) {
                const int m = c >> 7, rem = c & 127, r = rem >> 3, g = rem & 7;
                const uint4 v = *(const uint4*)(mT + (size_t)m * MT_S + (size_t)(ng + r) * 64 + (g << 3));
                *(uint4*)(&mst[m * 1024 + r * 64 + ((g ^ (r & 7)) << 3)]) = v;
            }
        }
        {
            const int r = tid >> 4, c4 = (tid & 15) << 2;
            const int n = ng + r;
            float4 v4;
            if (n < N_NODES) v4 = *(const float4*)&nf[(size_t)n * 64 + c4];
            else { v4.x = 0.f; v4.y = 0.f; v4.z = 0.f; v4.w = 0.f; }
            f16x4 h;
            h[0] = (f16)v4.x; h[1] = (f16)v4.y; h[2] = (f16)v4.z; h[3] = (f16)v4.w;
            const int g = c4 >> 3;
            *(f16x4*)&nft[r * 64 + ((g ^ (r & 7)) << 3) + (c4 & 7)] = h;
        }
        __syncthreads();

#pragma unroll
        for (int m = 0; m < 9; ++m) {
            const int l = (m == 0) ? 0 : ((m < 4) ? 1 : 2);
            f32x4 acc = zacc;
#pragma unroll
            for (int kk = 0; kk < 2; ++kk) {
                const int g = (kk << 2) + lg;
                const f16x8 b = *(const f16x8*)&mst[m * 1024 + lm * 64 + ((g ^ (lm & 7)) << 3)];
                acc = __builtin_amdgcn_mfma_f32_16x16x32_f16(wl[l][kk], b, acc, 0, 0, 0);
            }
#pragma unroll
            for (int i = 0; i < 4; ++i)
                outb[lm * 580 + ((w << 4) + r0 + i) * 9 + m] = acc[i] * 0.125f;
        }
        __syncthreads();

#pragma unroll
        for (int it = 0; it < 9; ++it) {
            const int c = it * 256 + tid;
            const int r = c / 144, q = c - r * 144;
            const int n = ng + r;
            if (n < N_NODES) {
                const float4 v = *(const float4*)&outb[r * 580 + (q << 2)];
                *(float4*)&out[(size_t)n * 576 + (q << 2)] = v;
            }
        }
        __syncthreads();

        {
            const float4 na4 = *(const float4*)&nas[((nt << 4) + lm) << 2];
            const float* nap = (const float*)&na4;
            f32x4 sacc = zacc;
#pragma unroll
            for (int kg = 0; kg < 8; ++kg) {
                const int g = ((kg & 1) << 2) + lg;
                f16x8 q = *(const f16x8*)&nft[lm * 64 + ((g ^ (lm & 7)) << 3)];
                const f16 sa = (f16)nap[kg >> 1];
                q = q * sa;
                sacc = __builtin_amdgcn_mfma_f32_16x16x32_f16(wsc[kg], q, sacc, 0, 0, 0);
            }
#pragma unroll
            for (int i = 0; i < 4; ++i)
                outb[lm * 580 + (w << 4) + r0 + i] = sacc[i] * 0.0625f;
        }
        __syncthreads();

        {
            const int r = tid >> 4, q = tid & 15;
            const int n = ng + r;
            if (n < N_NODES)
                *(float4*)&out[(size_t)MSG_OFF + (size_t)n * 576 + (q << 2)] =
                    *(const float4*)&outb[r * 580 + (q << 2)];
        }
        float4 z4; z4.x = 0.f; z4.y = 0.f; z4.z = 0.f; z4.w = 0.f;
#pragma unroll
        for (int it = 0; it < 8; ++it) {
            const int c = it * 256 + tid;
            const int r = c >> 7, q = c & 127;
            const int n = ng + r;
            if (n < N_NODES)
                *(float4*)&out[(size_t)MSG_OFF + (size_t)n * 576 + 64 + (q << 2)] = z4;
        }
    }
}

// ============================ fallback (atomic, fp32) path ============================

__device__ __forceinline__ void layer_accum(const float* src, const float* __restrict__ W,
                                            float a2[4][4], int c0, int e0) {
#pragma unroll
    for (int i = 0; i < 4; ++i)
#pragma unroll
        for (int j = 0; j < 4; ++j) a2[i][j] = 0.f;
#pragma unroll 8
    for (int u = 0; u < 64; ++u) {
        const float4 h4 = *(const float4*)&src[(u << 6) + e0];
        const float4 w4 = *(const float4*)&W[(u << 6) + c0];
        const float hv[4] = {h4.x, h4.y, h4.z, h4.w};
        const float wv[4] = {w4.x, w4.y, w4.z, w4.w};
#pragma unroll
        for (int i = 0; i < 4; ++i)
#pragma unroll
            for (int j = 0; j < 4; ++j) a2[i][j] += wv[i] * hv[j];
    }
}

__device__ __forceinline__ void layer_store(float* dst, const float a2[4][4],
                                            float scale, int c0, int e0) {
#pragma unroll
    for (int i = 0; i < 4; ++i) {
        float4 v;
        v.x = silu_f(a2[i][0] * scale);
        v.y = silu_f(a2[i][1] * scale);
        v.z = silu_f(a2[i][2] * scale);
        v.w = silu_f(a2[i][3] * scale);
        *(float4*)&dst[((c0 + i) << 6) + e0] = v;
    }
}

__global__ __launch_bounds__(256, 4)
void edge_kernel_atomic(const float* __restrict__ length,
                        const float* __restrict__ nf,
                        const float* __restrict__ ea,
                        const float* __restrict__ W1,
                        const float* __restrict__ W2,
                        const float* __restrict__ W3,
                        const float* __restrict__ W4,
                        const int*   __restrict__ eidx,
                        float* __restrict__ msg)
{
    __shared__ float buf[4096];
    __shared__ float lenS[512];
    __shared__ float Ys[576];
    __shared__ int   sendS[64];
    __shared__ int   recvS[64];

    const int tid = threadIdx.x;
    const int tx = tid & 15;
    const int ty = tid >> 4;
    const int c0 = tx << 2;
    const int e0 = ty << 2;
    const int ebase = blockIdx.x << 6;

    for (int i = tid; i < 512; i += 256) {
        const int e = i >> 3, k = i & 7;
        lenS[(k << 6) + e] = length[((ebase + e) << 3) + k];
    }
    for (int i = tid; i < 576; i += 256) Ys[i] = ea[ebase * 9 + i];
    if (tid < 64) {
        sendS[tid] = eidx[ebase + tid];
        recvS[tid] = eidx[N_EDGES + ebase + tid];
    }
    __syncthreads();

    {
        float a2[4][4];
#pragma unroll
        for (int i = 0; i < 4; ++i)
#pragma unroll
            for (int j = 0; j < 4; ++j) a2[i][j] = 0.f;
#pragma unroll
        for (int k = 0; k < 8; ++k) {
            const float4 h4 = *(const float4*)&lenS[(k << 6) + e0];
            const float4 w4 = *(const float4*)&W1[(k << 6) + c0];
            const float hv[4] = {h4.x, h4.y, h4.z, h4.w};
            const float wv[4] = {w4.x, w4.y, w4.z, w4.w};
#pragma unroll
            for (int i = 0; i < 4; ++i)
#pragma unroll
                for (int j = 0; j < 4; ++j) a2[i][j] += wv[i] * hv[j];
        }
        layer_store(buf, a2, 0.35355339059327373f, c0, e0);
    }
    __syncthreads();
    {
        float a2[4][4];
        layer_accum(buf, W2, a2, c0, e0);
        __syncthreads();
        layer_store(buf, a2, 0.125f, c0, e0);
    }
    __syncthreads();
    {
        float a2[4][4];
        layer_accum(buf, W3, a2, c0, e0);
        __syncthreads();
        layer_store(buf, a2, 0.125f, c0, e0);
    }
    __syncthreads();

    float wacc[3][4][4];
#pragma unroll
    for (int l = 0; l < 3; ++l)
#pragma unroll
        for (int i = 0; i < 4; ++i)
#pragma unroll
            for (int j = 0; j < 4; ++j) wacc[l][i][j] = 0.f;
#pragma unroll 4
    for (int u = 0; u < 64; ++u) {
        const float4 h4 = *(const float4*)&buf[(u << 6) + e0];
        const float hv[4] = {h4.x, h4.y, h4.z, h4.w};
#pragma unroll
        for (int l = 0; l < 3; ++l) {
            const float4 w4 = *(const float4*)&W4[u * 192 + (l << 6) + c0];
            const float wv[4] = {w4.x, w4.y, w4.z, w4.w};
#pragma unroll
            for (int i = 0; i < 4; ++i)
#pragma unroll
                for (int j = 0; j < 4; ++j) wacc[l][i][j] += wv[i] * hv[j];
        }
    }

#pragma unroll
    for (int j = 0; j < 4; ++j) {
        const int e = e0 + j;
        const int snd = sendS[e];
        const int rcv = recvS[e];
        const float4 nf4 = *(const float4*)&nf[(snd << 6) + c0];
        const float nfv[4] = {nf4.x, nf4.y, nf4.z, nf4.w};
        float* mrow = msg + rcv * MSG_ROW;
        const float y0 = Ys[e * 9 + 0];
        float y1[3], y2[5];
#pragma unroll
        for (int m = 0; m < 3; ++m) y1[m] = Ys[e * 9 + 1 + m];
#pragma unroll
        for (int m = 0; m < 5; ++m) y2[m] = Ys[e * 9 + 4 + m];
#pragma unroll
        for (int i = 0; i < 4; ++i) {
            const int c = c0 + i;
            const float wx0 = wacc[0][i][j] * 0.125f * nfv[i];
            const float wx1 = wacc[1][i][j] * 0.125f * nfv[i];
            const float wx2 = wacc[2][i][j] * 0.125f * nfv[i];
            atomicAdd(&mrow[c], wx0 * y0);
#pragma unroll
            for (int m = 0; m < 3; ++m) atomicAdd(&mrow[64 + c * 3 + m], wx1 * y1[m]);
#pragma unroll
            for (int m = 0; m < 5; ++m) atomicAdd(&mrow[256 + c * 5 + m], wx2 * y2[m]);
        }
    }
}

__global__ __launch_bounds__(256, 4)
void node_kernel(const float* __restrict__ nf,
                 const float* __restrict__ na,
                 const float* __restrict__ Wl,
                 const float* __restrict__ Wsc,
                 float* __restrict__ out)
{
    __shared__ float ms[4][576];
    __shared__ float fs[4][64];
    const int tid = threadIdx.x;
    const int wid = tid >> 6;
    const int v   = tid & 63;
    const int n   = (blockIdx.x << 2) + wid;
    const float* msg = out + MSG_OFF;

#pragma unroll
    for (int j = 0; j < 9; ++j)
        ms[wid][(j << 6) + v] = msg[n * MSG_ROW + (j << 6) + v];
    fs[wid][v] = nf[(n << 6) + v];
    __syncthreads();

    float o9[9];
#pragma unroll
    for (int j = 0; j < 9; ++j) o9[j] = 0.f;
    const float* m0 = &ms[wid][0];
    const float* m1 = &ms[wid][64];
    const float* m2 = &ms[wid][256];

#pragma unroll 8
    for (int u = 0; u < 64; ++u) {
        const float w0 = Wl[(u << 6) + v];
        const float w1 = Wl[4096 + (u << 6) + v];
        const float w2 = Wl[8192 + (u << 6) + v];
        o9[0] += m0[u] * w0;
        o9[1] += m1[u * 3 + 0] * w1;
        o9[2] += m1[u * 3 + 1] * w1;
        o9[3] += m1[u * 3 + 2] * w1;
        o9[4] += m2[u * 5 + 0] * w2;
        o9[5] += m2[u * 5 + 1] * w2;
        o9[6] += m2[u * 5 + 2] * w2;
        o9[7] += m2[u * 5 + 3] * w2;
        o9[8] += m2[u * 5 + 4] * w2;
    }
#pragma unroll
    for (int j = 0; j < 9; ++j) out[n * MSG_ROW + v * 9 + j] = o9[j] * 0.125f;

    const float b0 = na[(n << 2) + 0];
    const float b1 = na[(n << 2) + 1];
    const float b2 = na[(n << 2) + 2];
    const float b3 = na[(n << 2) + 3];
    float sacc = 0.f;
#pragma unroll 8
    for (int u = 0; u < 64; ++u) {
        const float f = fs[wid][u];
        sacc += f * (b0 * Wsc[(u << 6) + v] + b1 * Wsc[4096 + (u << 6) + v] +
                     b2 * Wsc[8192 + (u << 6) + v] + b3 * Wsc[12288 + (u << 6) + v]);
    }
    float* scrow = out + MSG_OFF + n * MSG_ROW;
    scrow[v] = sacc * 0.0625f;
#pragma unroll
    for (int j = 1; j < 9; ++j) scrow[(j << 6) + v] = 0.f;
}

extern "C" void kernel_launch(void* const* d_in, const int* in_sizes, int n_in,
                              void* d_out, int out_size, void* d_ws, size_t ws_size,
                              hipStream_t stream) {
    const float* length = (const float*)d_in[0];
    const float* nfeat  = (const float*)d_in[1];
    const float* nattr  = (const float*)d_in[2];
    const float* eattr  = (const float*)d_in[3];
    const float* W1     = (const float*)d_in[4];
    const float* W2     = (const float*)d_in[5];
    const float* W3     = (const float*)d_in[6];
    const float* W4     = (const float*)d_in[7];
    const float* Wl     = (const float*)d_in[8];
    const float* Wsc    = (const float*)d_in[9];
    const int*   eidx   = (const int*)d_in[10];
    float* out = (float*)d_out;

    // ws: wimg(102400B) | wx[E*192 f16] | mT[9*NPAD*64 f16] | counts|offs|cursor|order|bsum
    f16*    wimg   = (f16*)d_ws;
    __half* wx     = (__half*)((char*)d_ws + WIMG_BYTES);
    f16*    mT     = (f16*)((char*)d_ws + WIMG_BYTES + (size_t)N_EDGES * 192 * 2);
    int*   counts  = (int*)((char*)mT + (size_t)9 * MT_S * 2);
    int*   offsets = counts + N_NODES;
    int*   cursor  = offsets + N_NODES + 1;
    int*   order   = cursor + N_NODES;
    int*   bsum    = order + N_EDGES;
    const size_t need = WIMG_BYTES + (size_t)N_EDGES * 192 * 2 + (size_t)9 * MT_S * 2 +
                        (size_t)(N_NODES * 3 + 1 + N_EDGES + 128) * 4;

    if (ws_size >= need) {
        hipMemsetAsync(counts, 0, N_NODES * sizeof(int), stream);
        pre_kernel<<<WIMG_BLOCKS + N_EDGES / 256, 256, 0, stream>>>(W1, W2, W3, W4, Wl, Wsc,
                                                                    wimg, eidx, counts);
        scan1_kernel<<<NBLK_SCAN, SCAN_BS, 0, stream>>>(counts, offsets, bsum);
        scan3_kernel<<<NBLK_SCAN, SCAN_BS, 0, stream>>>(offsets, bsum, cursor);
        edge_mlp_mfma<<<N_EDGES / 128, 512, 0, stream>>>(length, nfeat, eidx, cursor, order,
                                                         wimg, (f16*)wx);
        gather_kernel<<<N_NODES / 4, 256, 0, stream>>>(wx, eattr, offsets, order, mT);
        node_mfma<<<NPAD / 64, 256, 0, stream>>>(wimg, mT, nfeat, nattr, out);
    } else {
        hipMemsetAsync(out + MSG_OFF, 0, (size_t)N_NODES * MSG_ROW * sizeof(float), stream);
        edge_kernel_atomic<<<N_EDGES / 64, 256, 0, stream>>>(length, nfeat, eattr,
                                                             W1, W2, W3, W4, eidx,
                                                             out + MSG_OFF);
        node_kernel<<<N_NODES / 4, 256, 0, stream>>>(nfeat, nattr, Wl, Wsc, out);
    }
}

// Round 13
// 146.389 us; speedup vs baseline: 1.0593x; 1.0413x over previous
//
#include <hip/hip_runtime.h>
#include <hip/hip_fp16.h>

#define N_NODES 20000
#define N_EDGES 320000
#define MSG_ROW 576
#define MSG_OFF 11520000   // N_NODES * 576 : sc region of d_out (fallback msg buffer)
#define SCAN_BS 256
#define NBLK_SCAN ((N_NODES + SCAN_BS - 1) / SCAN_BS)   // 79
#define NPAD 20032         // 313 * 64
#define MT_S (NPAD * 64)   // halfs per m-slice of mT

typedef _Float16 f16;
typedef _Float16 f16x4 __attribute__((ext_vector_type(4)));
typedef _Float16 f16x8 __attribute__((ext_vector_type(8)));
typedef float f32x4 __attribute__((ext_vector_type(4)));

// weight image (f16 elems): [Wt4 12288 | W1t 2048 | Wt2 4096 | Wt3 4096 | WlT 12288 | WscT 16384]
#define OFF_WLT  22528   // f16 index
#define OFF_WSCT 34816
#define WIMG_HALF 51200
#define WIMG_BYTES 102400
#define WIMG_BLOCKS 200  // 200*256 = 51200

// edge kernel LDS (bytes) — ROUND-10 PROVEN CONFIG (68us). Rounds 11/12 tested
// LDS 46080/33792 with weights-from-global: occupancy stayed ~36-38% in all
// three configs (LDS is NOT the limiter) while dur rose 68->73->84us. Full
// staging is fastest; do not move weight reads back to global.
#define OFF_WT4 0        // 192x64 f16 = 24576
#define OFF_W1T 24576    // 64x32 f16  = 4096  (k>=8 zero-padded)
#define OFF_WT2 28672    // 8192
#define OFF_WT3 36864    // 8192
#define OFF_H0  45056    // 128 x 32 f16 = 8192
#define OFF_HT  53248    // 128 x 64 f16 = 16384
#define LDS_TOTAL 69632
#define OFF_WXT 0        // wxT 128x192 f16 = 49152 B, aliases weights+H0 (dead after L4)

// silu via v_rcp_f32 (1 ulp): avoids the IEEE div sequence (~10 VALU ops/value,
// 48 values/thread x 3 layers). Tolerance headroom is ~3 orders of magnitude.
__device__ __forceinline__ float silu_f(float x) {
    return x * __builtin_amdgcn_rcpf(1.0f + __expf(-x));
}

// ============================ pre-kernel: weight image + histogram ============================

__global__ __launch_bounds__(256)
void pre_kernel(const float* __restrict__ W1, const float* __restrict__ W2,
                const float* __restrict__ W3, const float* __restrict__ W4,
                const float* __restrict__ Wl, const float* __restrict__ Wsc,
                f16* __restrict__ img,
                const int* __restrict__ eidx, int* __restrict__ counts) {
    const int b = blockIdx.x;
    if (b >= WIMG_BLOCKS) {
        const int e = (b - WIMG_BLOCKS) * 256 + threadIdx.x;
        if (e < N_EDGES) atomicAdd(&counts[eidx[N_EDGES + e]], 1);
        return;
    }
    const int p = b * 256 + threadIdx.x;
    float v;
    if (p < 12288) {                         // Wt4 [192][64] swizzled
        const int m = p >> 6, rem = p & 63, g = rem >> 3, j = rem & 7;
        const int k = ((g ^ (m & 7)) << 3) | j;
        v = W4[k * 192 + m];
    } else if (p < 14336) {                  // W1t [64][32], k>=8 -> 0
        const int q = p - 12288;
        const int m = q >> 5, rem = q & 31, g = rem >> 3, j = rem & 7;
        const int k = ((g ^ (m & 3)) << 3) | j;
        v = (k < 8) ? W1[k * 64 + m] : 0.f;
    } else if (p < 18432) {                  // Wt2 [64][64]
        const int q = p - 14336;
        const int m = q >> 6, rem = q & 63, g = rem >> 3, j = rem & 7;
        const int k = ((g ^ (m & 7)) << 3) | j;
        v = W2[k * 64 + m];
    } else if (p < 22528) {                  // Wt3 [64][64]
        const int q = p - 18432;
        const int m = q >> 6, rem = q & 63, g = rem >> 3, j = rem & 7;
        const int k = ((g ^ (m & 7)) << 3) | j;
        v = W3[k * 64 + m];
    } else if (p < OFF_WSCT) {               // WlT [l][v][u] linear (register frags)
        const int q = p - OFF_WLT;
        const int l = q >> 12, r = q & 4095, vv = r >> 6, u = r & 63;
        v = Wl[(l * 64 + u) * 64 + vv];
    } else {                                 // WscT [w][a*64+u] linear
        const int q = p - OFF_WSCT;
        const int ww = q >> 8, kk = q & 255, a = kk >> 6, u = kk & 63;
        v = Wsc[(a * 64 + u) * 64 + ww];
    }
    img[p] = (f16)v;
}

// ============================ CSR build (2 kernels) ============================

__global__ __launch_bounds__(SCAN_BS)
void scan1_kernel(const int* __restrict__ counts, int* __restrict__ offs,
                  int* __restrict__ bsum) {
    __shared__ int sm[SCAN_BS];
    const int tid = threadIdx.x;
    const int i = blockIdx.x * SCAN_BS + tid;
    const int v = (i < N_NODES) ? counts[i] : 0;
    sm[tid] = v;
    __syncthreads();
#pragma unroll
    for (int off = 1; off < SCAN_BS; off <<= 1) {
        const int t = (tid >= off) ? sm[tid - off] : 0;
        __syncthreads();
        sm[tid] += t;
        __syncthreads();
    }
    if (i < N_NODES) offs[i] = sm[tid] - v;          // block-local exclusive
    if (tid == SCAN_BS - 1) bsum[blockIdx.x] = sm[tid];
}

__global__ __launch_bounds__(SCAN_BS)
void scan3_kernel(int* __restrict__ offs, const int* __restrict__ bsum,
                  int* __restrict__ cursor) {
    __shared__ int bs[NBLK_SCAN];
    const int tid = threadIdx.x;
    if (tid < NBLK_SCAN) bs[tid] = bsum[tid];
    __syncthreads();
    int bbase = 0;
    for (int j = 0; j < blockIdx.x; ++j) bbase += bs[j];
    const int i = blockIdx.x * SCAN_BS + tid;
    if (i < N_NODES) {
        const int o = offs[i] + bbase;
        offs[i] = o;
        cursor[i] = o;
    }
    if (blockIdx.x == NBLK_SCAN - 1 && tid == SCAN_BS - 1)
        offs[N_NODES] = bbase + bs[NBLK_SCAN - 1];
}

// ============================ MFMA edge MLP (round-10 proven) + fused scatter ============================

__global__ __launch_bounds__(512, 4)
void edge_mlp_mfma(const float* __restrict__ length,
                   const float* __restrict__ nf,
                   const int*   __restrict__ eidx,
                   int* __restrict__ cursor,
                   int* __restrict__ order,
                   const f16*   __restrict__ wimg,
                   f16* __restrict__ wx)
{
    __shared__ __align__(16) char s[LDS_TOTAL];
    __shared__ int sendS[128];
    __shared__ int rankS[128];

    const int tid = threadIdx.x;
    const int ebase = blockIdx.x << 7;

    // ---- stage full weight image for edge MLP (2816 uint4 = 45056 B) ----
    {
        const uint4* src = (const uint4*)wimg;
        uint4* dst = (uint4*)s;
#pragma unroll
        for (int i = 0; i < 6; ++i) {
            const int c = i * 512 + tid;
            if (c < 2816) dst[c] = src[c];
        }
    }
    // ---- stage h0 (128 x 32 f16, k>=8 zeroed), swizzle mask 3; fused scatter ----
    if (tid < 128) {
        const int e = tid;
        const int eg = ebase + e;
        const float4 q0 = *(const float4*)&length[(size_t)eg * 8];
        const float4 q1 = *(const float4*)&length[(size_t)eg * 8 + 4];
        f16x8 h;
        h[0] = (f16)q0.x; h[1] = (f16)q0.y; h[2] = (f16)q0.z; h[3] = (f16)q0.w;
        h[4] = (f16)q1.x; h[5] = (f16)q1.y; h[6] = (f16)q1.z; h[7] = (f16)q1.w;
        *(f16x8*)(s + OFF_H0 + e * 64 + ((0 ^ (e & 3)) << 4)) = h;
        sendS[e] = eidx[eg];
        const int rcv = eidx[N_EDGES + eg];
        const int pos = atomicAdd(&cursor[rcv], 1);   // fused scatter
        order[pos] = eg;
        rankS[e] = pos;
    } else {
        const int idx = tid - 128;
        const int e = idx / 3, gz = 1 + idx - (idx / 3) * 3;
        uint4 z; z.x = 0; z.y = 0; z.z = 0; z.w = 0;
        *(uint4*)(s + OFF_H0 + e * 64 + ((gz ^ (e & 3)) << 4)) = z;
    }
    __syncthreads();

    const int lane = tid & 63, w = tid >> 6;
    const int eh = w >> 2, wm = w & 3;
    const int lm = lane & 15, lg = lane >> 4;
    const int mrow = wm * 16 + lm;
    const int r0 = lg << 2;
    const int eloc0 = eh << 6;

    const f32x4 zacc = {0.f, 0.f, 0.f, 0.f};
    f32x4 acc[4];

    // L1
    {
        const f16x8 a = *(const f16x8*)(s + OFF_W1T + mrow * 64 + ((lg ^ (mrow & 3)) << 4));
#pragma unroll
        for (int nt = 0; nt < 4; ++nt) {
            const int e = eloc0 + nt * 16 + lm;
            const f16x8 b = *(const f16x8*)(s + OFF_H0 + e * 64 + ((lg ^ (e & 3)) << 4));
            acc[nt] = __builtin_amdgcn_mfma_f32_16x16x32_f16(a, b, zacc, 0, 0, 0);
        }
    }
    {
        const int c = wm * 16 + r0;
#pragma unroll
        for (int nt = 0; nt < 4; ++nt) {
            const int e = eloc0 + nt * 16 + lm;
            f16x4 pk;
            pk[0] = (f16)silu_f(acc[nt][0] * 0.35355339059f);
            pk[1] = (f16)silu_f(acc[nt][1] * 0.35355339059f);
            pk[2] = (f16)silu_f(acc[nt][2] * 0.35355339059f);
            pk[3] = (f16)silu_f(acc[nt][3] * 0.35355339059f);
            *(f16x4*)(s + OFF_HT + e * 128 + (((c >> 3) ^ (e & 7)) << 4) + ((c & 7) << 1)) = pk;
        }
    }
    __syncthreads();

    // L2
#pragma unroll
    for (int nt = 0; nt < 4; ++nt) acc[nt] = zacc;
#pragma unroll
    for (int kh = 0; kh < 2; ++kh) {
        const int g = (kh << 2) + lg;
        const f16x8 a = *(const f16x8*)(s + OFF_WT2 + mrow * 128 + ((g ^ (mrow & 7)) << 4));
#pragma unroll
        for (int nt = 0; nt < 4; ++nt) {
            const int e = eloc0 + nt * 16 + lm;
            const f16x8 b = *(const f16x8*)(s + OFF_HT + e * 128 + ((g ^ (e & 7)) << 4));
            acc[nt] = __builtin_amdgcn_mfma_f32_16x16x32_f16(a, b, acc[nt], 0, 0, 0);
        }
    }
    __syncthreads();
    {
        const int c = wm * 16 + r0;
#pragma unroll
        for (int nt = 0; nt < 4; ++nt) {
            const int e = eloc0 + nt * 16 + lm;
            f16x4 pk;
            pk[0] = (f16)silu_f(acc[nt][0] * 0.125f);
            pk[1] = (f16)silu_f(acc[nt][1] * 0.125f);
            pk[2] = (f16)silu_f(acc[nt][2] * 0.125f);
            pk[3] = (f16)silu_f(acc[nt][3] * 0.125f);
            *(f16x4*)(s + OFF_HT + e * 128 + (((c >> 3) ^ (e & 7)) << 4) + ((c & 7) << 1)) = pk;
        }
    }
    __syncthreads();

    // L3
#pragma unroll
    for (int nt = 0; nt < 4; ++nt) acc[nt] = zacc;
#pragma unroll
    for (int kh = 0; kh < 2; ++kh) {
        const int g = (kh << 2) + lg;
        const f16x8 a = *(const f16x8*)(s + OFF_WT3 + mrow * 128 + ((g ^ (mrow & 7)) << 4));
#pragma unroll
        for (int nt = 0; nt < 4; ++nt) {
            const int e = eloc0 + nt * 16 + lm;
            const f16x8 b = *(const f16x8*)(s + OFF_HT + e * 128 + ((g ^ (e & 7)) << 4));
            acc[nt] = __builtin_amdgcn_mfma_f32_16x16x32_f16(a, b, acc[nt], 0, 0, 0);
        }
    }
    __syncthreads();
    {
        const int c = wm * 16 + r0;
#pragma unroll
        for (int nt = 0; nt < 4; ++nt) {
            const int e = eloc0 + nt * 16 + lm;
            f16x4 pk;
            pk[0] = (f16)silu_f(acc[nt][0] * 0.125f);
            pk[1] = (f16)silu_f(acc[nt][1] * 0.125f);
            pk[2] = (f16)silu_f(acc[nt][2] * 0.125f);
            pk[3] = (f16)silu_f(acc[nt][3] * 0.125f);
            *(f16x4*)(s + OFF_HT + e * 128 + (((c >> 3) ^ (e & 7)) << 4) + ((c & 7) << 1)) = pk;
        }
    }
    __syncthreads();

    // L4
    f32x4 acc4[3][4];
#pragma unroll
    for (int p = 0; p < 3; ++p)
#pragma unroll
        for (int nt = 0; nt < 4; ++nt) acc4[p][nt] = zacc;
#pragma unroll
    for (int kh = 0; kh < 2; ++kh) {
        const int g = (kh << 2) + lg;
        f16x8 ap[3];
#pragma unroll
        for (int p = 0; p < 3; ++p) {
            const int m4 = p * 64 + mrow;
            ap[p] = *(const f16x8*)(s + OFF_WT4 + m4 * 128 + ((g ^ (m4 & 7)) << 4));
        }
#pragma unroll
        for (int nt = 0; nt < 4; ++nt) {
            const int e = eloc0 + nt * 16 + lm;
            const f16x8 b = *(const f16x8*)(s + OFF_HT + e * 128 + ((g ^ (e & 7)) << 4));
#pragma unroll
            for (int p = 0; p < 3; ++p)
                acc4[p][nt] = __builtin_amdgcn_mfma_f32_16x16x32_f16(ap[p], b, acc4[p][nt], 0, 0, 0);
        }
    }
    __syncthreads();   // weight reads done -> wxT may alias weights+H0

#pragma unroll
    for (int nt = 0; nt < 4; ++nt) {
        const int e = eloc0 + nt * 16 + lm;
        const int snd = sendS[e];
        const float4 nf4 = *(const float4*)&nf[(size_t)snd * 64 + wm * 16 + r0];
#pragma unroll
        for (int p = 0; p < 3; ++p) {
            const int c = p * 64 + wm * 16 + r0;
            f16x4 pk;
            pk[0] = (f16)(acc4[p][nt][0] * 0.125f * nf4.x);
            pk[1] = (f16)(acc4[p][nt][1] * 0.125f * nf4.y);
            pk[2] = (f16)(acc4[p][nt][2] * 0.125f * nf4.z);
            pk[3] = (f16)(acc4[p][nt][3] * 0.125f * nf4.w);
            *(f16x4*)(s + OFF_WXT + e * 384 + (((c >> 3) ^ (e & 7)) << 4) + ((c & 7) << 1)) = pk;
        }
    }
    __syncthreads();

#pragma unroll
    for (int it = 0; it < 6; ++it) {
        const int chunk = it * 512 + tid;
        const int e = chunk / 24, g = chunk - e * 24;
        const uint4 v = *(const uint4*)(s + OFF_WXT + e * 384 + ((g ^ (e & 7)) << 4));
        *(uint4*)((char*)wx + (size_t)rankS[e] * 384 + g * 16) = v;
    }
}

// ============================ gather: streaming wx -> mT fp16 [m][n][u] ============================
// (round-8 verified; 20000 waves of TLP — do NOT fuse into node_mfma, round-9
// showed that collapses parallelism 16x and regresses 2.5x)

__global__ __launch_bounds__(256, 8)
void gather_kernel(const __half* __restrict__ wx,     // E x 192 f16, receiver-sorted
                   const float* __restrict__ ea,      // E x 9
                   const int* __restrict__ offs,      // N+1
                   const int* __restrict__ order,     // E (for ea lookup only)
                   f16* __restrict__ mT)              // 9 x NPAD x 64
{
    const int tid = threadIdx.x;
    const int wid = tid >> 6;
    const int v   = tid & 63;
    const int n   = (blockIdx.x << 2) + wid;
    const int beg = offs[n];
    const int end = offs[n + 1];

    float a0 = 0.f, a1[3] = {0.f, 0.f, 0.f}, a2[5] = {0.f, 0.f, 0.f, 0.f, 0.f};
    int k = beg;
    for (; k + 2 <= end; k += 2) {
        const int eA = __builtin_amdgcn_readfirstlane(order[k]);
        const int eB = __builtin_amdgcn_readfirstlane(order[k + 1]);
        const __half* wrA = wx + (size_t)k * 192;         // sequential
        const __half* wrB = wx + (size_t)(k + 1) * 192;
        const float xA0 = __half2float(wrA[v]);
        const float xA1 = __half2float(wrA[64 + v]);
        const float xA2 = __half2float(wrA[128 + v]);
        const float xB0 = __half2float(wrB[v]);
        const float xB1 = __half2float(wrB[64 + v]);
        const float xB2 = __half2float(wrB[128 + v]);
        const float* yA = ea + (size_t)eA * 9;
        const float* yB = ea + (size_t)eB * 9;
        a0 += xA0 * yA[0] + xB0 * yB[0];
#pragma unroll
        for (int m = 0; m < 3; ++m) a1[m] += xA1 * yA[1 + m] + xB1 * yB[1 + m];
#pragma unroll
        for (int m = 0; m < 5; ++m) a2[m] += xA2 * yA[4 + m] + xB2 * yB[4 + m];
    }
    if (k < end) {
        const int e = __builtin_amdgcn_readfirstlane(order[k]);
        const __half* wr = wx + (size_t)k * 192;
        const float x0 = __half2float(wr[v]);
        const float x1 = __half2float(wr[64 + v]);
        const float x2 = __half2float(wr[128 + v]);
        const float* y = ea + (size_t)e * 9;
        a0 += x0 * y[0];
#pragma unroll
        for (int m = 0; m < 3; ++m) a1[m] += x1 * y[1 + m];
#pragma unroll
        for (int m = 0; m < 5; ++m) a2[m] += x2 * y[4 + m];
    }

    f16* base = mT + (size_t)n * 64 + v;
    base[0] = (f16)a0;
#pragma unroll
    for (int m = 0; m < 3; ++m) base[(size_t)(1 + m) * MT_S] = (f16)a1[m];
#pragma unroll
    for (int m = 0; m < 5; ++m) base[(size_t)(4 + m) * MT_S] = (f16)a2[m];
}

// ============================ MFMA node transform v2 (round-7/8 verified) ============================

__global__ __launch_bounds__(256, 2)
void node_mfma(const f16* __restrict__ wimg,
               const f16* __restrict__ mT,      // 9 x NPAD x 64
               const float* __restrict__ nf,    // N x 64
               const float* __restrict__ na,    // N x 4
               float* __restrict__ out)
{
    __shared__ __align__(16) f16  mst[9 * 16 * 64];   // [m][r][u] swizzled
    __shared__ __align__(16) f16  nft[16 * 64];
    __shared__ __align__(16) float nas[256];
    __shared__ __align__(16) float outb[16 * 580];

    const int tid = threadIdx.x;
    const int lane = tid & 63, w = tid >> 6;
    const int lm = lane & 15, lg = lane >> 4;
    const int r0 = lg << 2;
    const int n0 = blockIdx.x << 6;

    const f16* wlT  = wimg + OFF_WLT;
    const f16* wscT = wimg + OFF_WSCT;
    f16x8 wl[3][2];
#pragma unroll
    for (int l = 0; l < 3; ++l)
#pragma unroll
        for (int kk = 0; kk < 2; ++kk)
            wl[l][kk] = *(const f16x8*)(wlT + ((l << 6) + (w << 4) + lm) * 64 + (kk << 5) + (lg << 3));
    f16x8 wsc[8];
#pragma unroll
    for (int kg = 0; kg < 8; ++kg)
        wsc[kg] = *(const f16x8*)(wscT + ((w << 4) + lm) * 256 + (kg << 5) + (lg << 3));

    {
        const int n = n0 + (tid >> 2);
        nas[tid] = (n < N_NODES) ? na[(size_t)n * 4 + (tid & 3)] : 0.f;
    }

    const f32x4 zacc = {0.f, 0.f, 0.f, 0.f};

    for (int nt = 0; nt < 4; ++nt) {
        const int ng = n0 + (nt << 4);
        __syncthreads();

#pragma unroll
        for (int it = 0; it < 5; ++it) {
            const int c = it * 256 + tid;
            if (c < 1152) {
                const int m = c >> 7, rem = c & 127, r = rem >> 3, g = rem & 7;
                const uint4 v = *(const uint4*)(mT + (size_t)m * MT_S + (size_t)(ng + r) * 64 + (g << 3));
                *(uint4*)(&mst[m * 1024 + r * 64 + ((g ^ (r & 7)) << 3)]) = v;
            }
        }
        {
            const int r = tid >> 4, c4 = (tid & 15) << 2;
            const int n = ng + r;
            float4 v4;
            if (n < N_NODES) v4 = *(const float4*)&nf[(size_t)n * 64 + c4];
            else { v4.x = 0.f; v4.y = 0.f; v4.z = 0.f; v4.w = 0.f; }
            f16x4 h;
            h[0] = (f16)v4.x; h[1] = (f16)v4.y; h[2] = (f16)v4.z; h[3] = (f16)v4.w;
            const int g = c4 >> 3;
            *(f16x4*)&nft[r * 64 + ((g ^ (r & 7)) << 3) + (c4 & 7)] = h;
        }
        __syncthreads();

#pragma unroll
        for (int m = 0; m < 9; ++m) {
            const int l = (m == 0) ? 0 : ((m < 4) ? 1 : 2);
            f32x4 acc = zacc;
#pragma unroll
            for (int kk = 0; kk < 2; ++kk) {
                const int g = (kk << 2) + lg;
                const f16x8 b = *(const f16x8*)&mst[m * 1024 + lm * 64 + ((g ^ (lm & 7)) << 3)];
                acc = __builtin_amdgcn_mfma_f32_16x16x32_f16(wl[l][kk], b, acc, 0, 0, 0);
            }
#pragma unroll
            for (int i = 0; i < 4; ++i)
                outb[lm * 580 + ((w << 4) + r0 + i) * 9 + m] = acc[i] * 0.125f;
        }
        __syncthreads();

#pragma unroll
        for (int it = 0; it < 9; ++it) {
            const int c = it * 256 + tid;
            const int r = c / 144, q = c - r * 144;
            const int n = ng + r;
            if (n < N_NODES) {
                const float4 v = *(const float4*)&outb[r * 580 + (q << 2)];
                *(float4*)&out[(size_t)n * 576 + (q << 2)] = v;
            }
        }
        __syncthreads();

        {
            const float4 na4 = *(const float4*)&nas[((nt << 4) + lm) << 2];
            const float* nap = (const float*)&na4;
            f32x4 sacc = zacc;
#pragma unroll
            for (int kg = 0; kg < 8; ++kg) {
                const int g = ((kg & 1) << 2) + lg;
                f16x8 q = *(const f16x8*)&nft[lm * 64 + ((g ^ (lm & 7)) << 3)];
                const f16 sa = (f16)nap[kg >> 1];
                q = q * sa;
                sacc = __builtin_amdgcn_mfma_f32_16x16x32_f16(wsc[kg], q, sacc, 0, 0, 0);
            }
#pragma unroll
            for (int i = 0; i < 4; ++i)
                outb[lm * 580 + (w << 4) + r0 + i] = sacc[i] * 0.0625f;
        }
        __syncthreads();

        {
            const int r = tid >> 4, q = tid & 15;
            const int n = ng + r;
            if (n < N_NODES)
                *(float4*)&out[(size_t)MSG_OFF + (size_t)n * 576 + (q << 2)] =
                    *(const float4*)&outb[r * 580 + (q << 2)];
        }
        float4 z4; z4.x = 0.f; z4.y = 0.f; z4.z = 0.f; z4.w = 0.f;
#pragma unroll
        for (int it = 0; it < 8; ++it) {
            const int c = it * 256 + tid;
            const int r = c >> 7, q = c & 127;
            const int n = ng + r;
            if (n < N_NODES)
                *(float4*)&out[(size_t)MSG_OFF + (size_t)n * 576 + 64 + (q << 2)] = z4;
        }
    }
}

// ============================ fallback (atomic, fp32) path ============================

__device__ __forceinline__ void layer_accum(const float* src, const float* __restrict__ W,
                                            float a2[4][4], int c0, int e0) {
#pragma unroll
    for (int i = 0; i < 4; ++i)
#pragma unroll
        for (int j = 0; j < 4; ++j) a2[i][j] = 0.f;
#pragma unroll 8
    for (int u = 0; u < 64; ++u) {
        const float4 h4 = *(const float4*)&src[(u << 6) + e0];
        const float4 w4 = *(const float4*)&W[(u << 6) + c0];
        const float hv[4] = {h4.x, h4.y, h4.z, h4.w};
        const float wv[4] = {w4.x, w4.y, w4.z, w4.w};
#pragma unroll
        for (int i = 0; i < 4; ++i)
#pragma unroll
            for (int j = 0; j < 4; ++j) a2[i][j] += wv[i] * hv[j];
    }
}

__device__ __forceinline__ void layer_store(float* dst, const float a2[4][4],
                                            float scale, int c0, int e0) {
#pragma unroll
    for (int i = 0; i < 4; ++i) {
        float4 v;
        v.x = silu_f(a2[i][0] * scale);
        v.y = silu_f(a2[i][1] * scale);
        v.z = silu_f(a2[i][2] * scale);
        v.w = silu_f(a2[i][3] * scale);
        *(float4*)&dst[((c0 + i) << 6) + e0] = v;
    }
}

__global__ __launch_bounds__(256, 4)
void edge_kernel_atomic(const float* __restrict__ length,
                        const float* __restrict__ nf,
                        const float* __restrict__ ea,
                        const float* __restrict__ W1,
                        const float* __restrict__ W2,
                        const float* __restrict__ W3,
                        const float* __restrict__ W4,
                        const int*   __restrict__ eidx,
                        float* __restrict__ msg)
{
    __shared__ float buf[4096];
    __shared__ float lenS[512];
    __shared__ float Ys[576];
    __shared__ int   sendS[64];
    __shared__ int   recvS[64];

    const int tid = threadIdx.x;
    const int tx = tid & 15;
    const int ty = tid >> 4;
    const int c0 = tx << 2;
    const int e0 = ty << 2;
    const int ebase = blockIdx.x << 6;

    for (int i = tid; i < 512; i += 256) {
        const int e = i >> 3, k = i & 7;
        lenS[(k << 6) + e] = length[((ebase + e) << 3) + k];
    }
    for (int i = tid; i < 576; i += 256) Ys[i] = ea[ebase * 9 + i];
    if (tid < 64) {
        sendS[tid] = eidx[ebase + tid];
        recvS[tid] = eidx[N_EDGES + ebase + tid];
    }
    __syncthreads();

    {
        float a2[4][4];
#pragma unroll
        for (int i = 0; i < 4; ++i)
#pragma unroll
            for (int j = 0; j < 4; ++j) a2[i][j] = 0.f;
#pragma unroll
        for (int k = 0; k < 8; ++k) {
            const float4 h4 = *(const float4*)&lenS[(k << 6) + e0];
            const float4 w4 = *(const float4*)&W1[(k << 6) + c0];
            const float hv[4] = {h4.x, h4.y, h4.z, h4.w};
            const float wv[4] = {w4.x, w4.y, w4.z, w4.w};
#pragma unroll
            for (int i = 0; i < 4; ++i)
#pragma unroll
                for (int j = 0; j < 4; ++j) a2[i][j] += wv[i] * hv[j];
        }
        layer_store(buf, a2, 0.35355339059327373f, c0, e0);
    }
    __syncthreads();
    {
        float a2[4][4];
        layer_accum(buf, W2, a2, c0, e0);
        __syncthreads();
        layer_store(buf, a2, 0.125f, c0, e0);
    }
    __syncthreads();
    {
        float a2[4][4];
        layer_accum(buf, W3, a2, c0, e0);
        __syncthreads();
        layer_store(buf, a2, 0.125f, c0, e0);
    }
    __syncthreads();

    float wacc[3][4][4];
#pragma unroll
    for (int l = 0; l < 3; ++l)
#pragma unroll
        for (int i = 0; i < 4; ++i)
#pragma unroll
            for (int j = 0; j < 4; ++j) wacc[l][i][j] = 0.f;
#pragma unroll 4
    for (int u = 0; u < 64; ++u) {
        const float4 h4 = *(const float4*)&buf[(u << 6) + e0];
        const float hv[4] = {h4.x, h4.y, h4.z, h4.w};
#pragma unroll
        for (int l = 0; l < 3; ++l) {
            const float4 w4 = *(const float4*)&W4[u * 192 + (l << 6) + c0];
            const float wv[4] = {w4.x, w4.y, w4.z, w4.w};
#pragma unroll
            for (int i = 0; i < 4; ++i)
#pragma unroll
                for (int j = 0; j < 4; ++j) wacc[l][i][j] += wv[i] * hv[j];
        }
    }

#pragma unroll
    for (int j = 0; j < 4; ++j) {
        const int e = e0 + j;
        const int snd = sendS[e];
        const int rcv = recvS[e];
        const float4 nf4 = *(const float4*)&nf[(snd << 6) + c0];
        const float nfv[4] = {nf4.x, nf4.y, nf4.z, nf4.w};
        float* mrow = msg + rcv * MSG_ROW;
        const float y0 = Ys[e * 9 + 0];
        float y1[3], y2[5];
#pragma unroll
        for (int m = 0; m < 3; ++m) y1[m] = Ys[e * 9 + 1 + m];
#pragma unroll
        for (int m = 0; m < 5; ++m) y2[m] = Ys[e * 9 + 4 + m];
#pragma unroll
        for (int i = 0; i < 4; ++i) {
            const int c = c0 + i;
            const float wx0 = wacc[0][i][j] * 0.125f * nfv[i];
            const float wx1 = wacc[1][i][j] * 0.125f * nfv[i];
            const float wx2 = wacc[2][i][j] * 0.125f * nfv[i];
            atomicAdd(&mrow[c], wx0 * y0);
#pragma unroll
            for (int m = 0; m < 3; ++m) atomicAdd(&mrow[64 + c * 3 + m], wx1 * y1[m]);
#pragma unroll
            for (int m = 0; m < 5; ++m) atomicAdd(&mrow[256 + c * 5 + m], wx2 * y2[m]);
        }
    }
}

__global__ __launch_bounds__(256, 4)
void node_kernel(const float* __restrict__ nf,
                 const float* __restrict__ na,
                 const float* __restrict__ Wl,
                 const float* __restrict__ Wsc,
                 float* __restrict__ out)
{
    __shared__ float ms[4][576];
    __shared__ float fs[4][64];
    const int tid = threadIdx.x;
    const int wid = tid >> 6;
    const int v   = tid & 63;
    const int n   = (blockIdx.x << 2) + wid;
    const float* msg = out + MSG_OFF;

#pragma unroll
    for (int j = 0; j < 9; ++j)
        ms[wid][(j << 6) + v] = msg[n * MSG_ROW + (j << 6) + v];
    fs[wid][v] = nf[(n << 6) + v];
    __syncthreads();

    float o9[9];
#pragma unroll
    for (int j = 0; j < 9; ++j) o9[j] = 0.f;
    const float* m0 = &ms[wid][0];
    const float* m1 = &ms[wid][64];
    const float* m2 = &ms[wid][256];

#pragma unroll 8
    for (int u = 0; u < 64; ++u) {
        const float w0 = Wl[(u << 6) + v];
        const float w1 = Wl[4096 + (u << 6) + v];
        const float w2 = Wl[8192 + (u << 6) + v];
        o9[0] += m0[u] * w0;
        o9[1] += m1[u * 3 + 0] * w1;
        o9[2] += m1[u * 3 + 1] * w1;
        o9[3] += m1[u * 3 + 2] * w1;
        o9[4] += m2[u * 5 + 0] * w2;
        o9[5] += m2[u * 5 + 1] * w2;
        o9[6] += m2[u * 5 + 2] * w2;
        o9[7] += m2[u * 5 + 3] * w2;
        o9[8] += m2[u * 5 + 4] * w2;
    }
#pragma unroll
    for (int j = 0; j < 9; ++j) out[n * MSG_ROW + v * 9 + j] = o9[j] * 0.125f;

    const float b0 = na[(n << 2) + 0];
    const float b1 = na[(n << 2) + 1];
    const float b2 = na[(n << 2) + 2];
    const float b3 = na[(n << 2) + 3];
    float sacc = 0.f;
#pragma unroll 8
    for (int u = 0; u < 64; ++u) {
        const float f = fs[wid][u];
        sacc += f * (b0 * Wsc[(u << 6) + v] + b1 * Wsc[4096 + (u << 6) + v] +
                     b2 * Wsc[8192 + (u << 6) + v] + b3 * Wsc[12288 + (u << 6) + v]);
    }
    float* scrow = out + MSG_OFF + n * MSG_ROW;
    scrow[v] = sacc * 0.0625f;
#pragma unroll
    for (int j = 1; j < 9; ++j) scrow[(j << 6) + v] = 0.f;
}

extern "C" void kernel_launch(void* const* d_in, const int* in_sizes, int n_in,
                              void* d_out, int out_size, void* d_ws, size_t ws_size,
                              hipStream_t stream) {
    const float* length = (const float*)d_in[0];
    const float* nfeat  = (const float*)d_in[1];
    const float* nattr  = (const float*)d_in[2];
    const float* eattr  = (const float*)d_in[3];
    const float* W1     = (const float*)d_in[4];
    const float* W2     = (const float*)d_in[5];
    const float* W3     = (const float*)d_in[6];
    const float* W4     = (const float*)d_in[7];
    const float* Wl     = (const float*)d_in[8];
    const float* Wsc    = (const float*)d_in[9];
    const int*   eidx   = (const int*)d_in[10];
    float* out = (float*)d_out;

    // ws: wimg(102400B) | wx[E*192 f16] | mT[9*NPAD*64 f16] | counts|offs|cursor|order|bsum
    f16*    wimg   = (f16*)d_ws;
    __half* wx     = (__half*)((char*)d_ws + WIMG_BYTES);
    f16*    mT     = (f16*)((char*)d_ws + WIMG_BYTES + (size_t)N_EDGES * 192 * 2);
    int*   counts  = (int*)((char*)mT + (size_t)9 * MT_S * 2);
    int*   offsets = counts + N_NODES;
    int*   cursor  = offsets + N_NODES + 1;
    int*   order   = cursor + N_NODES;
    int*   bsum    = order + N_EDGES;
    const size_t need = WIMG_BYTES + (size_t)N_EDGES * 192 * 2 + (size_t)9 * MT_S * 2 +
                        (size_t)(N_NODES * 3 + 1 + N_EDGES + 128) * 4;

    if (ws_size >= need) {
        hipMemsetAsync(counts, 0, N_NODES * sizeof(int), stream);
        pre_kernel<<<WIMG_BLOCKS + N_EDGES / 256, 256, 0, stream>>>(W1, W2, W3, W4, Wl, Wsc,
                                                                    wimg, eidx, counts);
        scan1_kernel<<<NBLK_SCAN, SCAN_BS, 0, stream>>>(counts, offsets, bsum);
        scan3_kernel<<<NBLK_SCAN, SCAN_BS, 0, stream>>>(offsets, bsum, cursor);
        edge_mlp_mfma<<<N_EDGES / 128, 512, 0, stream>>>(length, nfeat, eidx, cursor, order,
                                                         wimg, (f16*)wx);
        gather_kernel<<<N_NODES / 4, 256, 0, stream>>>(wx, eattr, offsets, order, mT);
        node_mfma<<<NPAD / 64, 256, 0, stream>>>(wimg, mT, nfeat, nattr, out);
    } else {
        hipMemsetAsync(out + MSG_OFF, 0, (size_t)N_NODES * MSG_ROW * sizeof(float), stream);
        edge_kernel_atomic<<<N_EDGES / 64, 256, 0, stream>>>(length, nfeat, eattr,
                                                             W1, W2, W3, W4, eidx,
                                                             out + MSG_OFF);
        node_kernel<<<N_NODES / 4, 256, 0, stream>>>(nfeat, nattr, Wl, Wsc, out);
    }
}